// Round 1
// baseline (10753.287 us; speedup 1.0000x reference)
//
#include <hip/hip_runtime.h>
#include <cstddef>
#include <cstdint>

#define B_DIM 4
#define T_DIM 1024
#define D_DIM 1024
#define H_DIM 16
#define DH 64
#define JDIM 2048
#define MEMLEN 1024

#define TILE 64
#define BK 16

// ---------------------------------------------------------------------------
// mem_next = x  (t == mem_len, so concat([mem,x])[:, -1024:] == x)
// ---------------------------------------------------------------------------
__global__ __launch_bounds__(256) void copy_kernel(const float* __restrict__ src,
                                                   float* __restrict__ dst) {
    size_t idx = ((size_t)blockIdx.x * 256 + threadIdx.x) * 4;
    float4 v = *(const float4*)(src + idx);
    *(float4*)(dst + idx) = v;
}

// ---------------------------------------------------------------------------
// fp32 tiled GEMM, 64x64 tile, BK=16, 256 threads, 4x4 micro-tile per thread.
// MODE 0: q = x @ wq            -> qh[b][h][i][c]        (M=4096, N=1024)
// MODE 1: kv = [mem;x] @ wkv    -> kt[b][h][j][c], v[..] (M=8192, N=2048)
// MODE 2: out = o @ wo + bo     -> C row-major           (M=4096, N=1024)
// ---------------------------------------------------------------------------
template <int MODE>
__global__ __launch_bounds__(256) void gemm_tiled(
    const float* __restrict__ A0, const float* __restrict__ A1,
    const float* __restrict__ B, const float* __restrict__ bias,
    float* __restrict__ C0, float* __restrict__ C1) {
    constexpr int N = (MODE == 1) ? 2048 : 1024;
    constexpr int K = 1024;
    __shared__ float As[BK][TILE + 4];   // [k][m], +4 pad keeps 16B align + banks
    __shared__ float Bs[BK][TILE];       // [k][n]

    const int tid = threadIdx.x;
    const int row0 = blockIdx.y * TILE;
    const int col0 = blockIdx.x * TILE;

    // A staging: thread loads float4 at (row0 + tid/4, k0 + (tid%4)*4)
    const int lm = tid >> 2;
    const int lk = (tid & 3) << 2;
    const int arow = row0 + lm;
    const float* aptr;
    if (MODE == 1) {
        int b = arow >> 11, jj = arow & 2047;
        aptr = (jj < MEMLEN) ? (A0 + ((size_t)b * MEMLEN + jj) * K)
                             : (A1 + ((size_t)b * T_DIM + (jj - MEMLEN)) * K);
    } else {
        aptr = A0 + (size_t)arow * K;
    }
    // B staging: thread loads float4 at (k0 + tid/16, col0 + (tid%16)*4)
    const int bk = tid >> 4;
    const int bn = (tid & 15) << 2;

    const int ty = tid >> 4, tx = tid & 15;
    float acc[4][4] = {};

    for (int k0 = 0; k0 < K; k0 += BK) {
        float4 av = *(const float4*)(aptr + k0 + lk);
        As[lk + 0][lm] = av.x;
        As[lk + 1][lm] = av.y;
        As[lk + 2][lm] = av.z;
        As[lk + 3][lm] = av.w;
        *(float4*)&Bs[bk][bn] = *(const float4*)(B + (size_t)(k0 + bk) * N + col0 + bn);
        __syncthreads();
#pragma unroll
        for (int kk = 0; kk < BK; ++kk) {
            float ar[4], br[4];
            *(float4*)ar = *(const float4*)&As[kk][ty << 2];
            *(float4*)br = *(const float4*)&Bs[kk][tx << 2];
#pragma unroll
            for (int ii = 0; ii < 4; ++ii)
#pragma unroll
                for (int jj = 0; jj < 4; ++jj) acc[ii][jj] += ar[ii] * br[jj];
        }
        __syncthreads();
    }

#pragma unroll
    for (int ii = 0; ii < 4; ++ii) {
        const int r = row0 + (ty << 2) + ii;
#pragma unroll
        for (int jj = 0; jj < 4; ++jj) {
            const int n = col0 + (tx << 2) + jj;
            const float val = acc[ii][jj];
            if (MODE == 0) {
                int b = r >> 10, i = r & 1023, h = n >> 6, c = n & 63;
                C0[(((size_t)b * H_DIM + h) * T_DIM + i) * DH + c] = val;
            } else if (MODE == 1) {
                int b = r >> 11, j = r & 2047;
                if (n < 1024) {
                    int h = n >> 6, c = n & 63;
                    C0[(((size_t)b * H_DIM + h) * JDIM + j) * DH + c] = val;
                } else {
                    int n2 = n - 1024, h = n2 >> 6, c = n2 & 63;
                    C1[(((size_t)b * H_DIM + h) * JDIM + j) * DH + c] = val;
                }
            } else {
                C0[(size_t)r * 1024 + n] = val + bias[n];
            }
        }
    }
}

// ---------------------------------------------------------------------------
// kt (bh, j, c) -> kT (bh, c, j)   32x32 LDS tile transpose
// ---------------------------------------------------------------------------
__global__ __launch_bounds__(256) void transpose_k_kernel(const float* __restrict__ kt,
                                                          float* __restrict__ kT) {
    __shared__ float tile[32][33];
    const int bh = blockIdx.z;
    const int j0 = blockIdx.x * 32, c0 = blockIdx.y * 32;
    const int tx = threadIdx.x, ty = threadIdx.y;
    for (int r = ty; r < 32; r += 8)
        tile[r][tx] = kt[((size_t)bh * JDIM + j0 + r) * DH + c0 + tx];
    __syncthreads();
    for (int r = ty; r < 32; r += 8)
        kT[((size_t)bh * DH + c0 + r) * JDIM + j0 + tx] = tile[tx][r];
}

// rel_w (jp, h, c) -> relT (h, c, jp)
__global__ __launch_bounds__(256) void transpose_rel_kernel(const float* __restrict__ rel,
                                                            float* __restrict__ relT) {
    __shared__ float tile[32][33];
    const int h = blockIdx.z;
    const int j0 = blockIdx.x * 32, c0 = blockIdx.y * 32;
    const int tx = threadIdx.x, ty = threadIdx.y;
    for (int r = ty; r < 32; r += 8)
        tile[r][tx] = rel[((size_t)(j0 + r) * H_DIM + h) * DH + c0 + tx];
    __syncthreads();
    for (int r = ty; r < 32; r += 8)
        relT[((size_t)h * DH + c0 + r) * JDIM + j0 + tx] = tile[tx][r];
}

// ---------------------------------------------------------------------------
// Attention: one block (256 thr) per (b,h,i) query row.
// s[j] = scale*(q_i . k_j + q_i . rel[j+1023-i]) for j <= i+1024, else -inf.
// softmax over j, o = p @ V; 1/l folded into final scale.
// ---------------------------------------------------------------------------
__global__ __launch_bounds__(256) void attn_kernel(
    const float* __restrict__ qh, const float* __restrict__ kT,
    const float* __restrict__ vv, const float* __restrict__ relT,
    float* __restrict__ o) {
    const int i = blockIdx.x;
    const int bh = blockIdx.y;
    const int h = bh & (H_DIM - 1);

    __shared__ float qs[DH];
    __shared__ float s[JDIM];
    __shared__ float red[8];
    __shared__ float ored[4][DH];

    const int tid = threadIdx.x;
    const int wave = tid >> 6, lane = tid & 63;

    if (tid < DH) qs[tid] = qh[((size_t)bh * T_DIM + i) * DH + tid];
    __syncthreads();

    const int valid = i + MEMLEN + 1;  // = i + 1025, <= 2048
    const float scale = 0.125f;        // dh^-0.5
    const float* kbase = kT + (size_t)bh * DH * JDIM;
    const float* rbase = relT + (size_t)h * DH * JDIM;
    const int shiftoff = MEMLEN - 1 - i;  // rel index = j + 1023 - i

    // ---- scores ----
    for (int j0 = wave * 64; j0 < JDIM; j0 += 256) {
        const int j = j0 + lane;
        if (j < valid) {
            float acc = 0.f;
            const int jp = j + shiftoff;
#pragma unroll
            for (int c = 0; c < DH; ++c)
                acc += qs[c] * (kbase[(size_t)c * JDIM + j] + rbase[(size_t)c * JDIM + jp]);
            s[j] = acc * scale;
        } else {
            s[j] = -__builtin_inff();
        }
    }
    __syncthreads();

    // ---- max reduce ----
    float m = -__builtin_inff();
    for (int j = tid; j < JDIM; j += 256) m = fmaxf(m, s[j]);
#pragma unroll
    for (int off = 32; off > 0; off >>= 1) m = fmaxf(m, __shfl_down(m, off));
    if (lane == 0) red[wave] = m;
    __syncthreads();
    m = fmaxf(fmaxf(red[0], red[1]), fmaxf(red[2], red[3]));

    // ---- exp + sum reduce ----
    float lsum = 0.f;
    for (int j = tid; j < JDIM; j += 256) {
        float e = __expf(s[j] - m);  // -inf -> 0
        s[j] = e;
        lsum += e;
    }
#pragma unroll
    for (int off = 32; off > 0; off >>= 1) lsum += __shfl_down(lsum, off);
    if (lane == 0) red[4 + wave] = lsum;
    __syncthreads();  // also publishes s[j] = p_j (unnormalized)
    const float rinv = 1.f / (red[4] + red[5] + red[6] + red[7]);

    // ---- o = p @ V ---- (wave w covers j-quarter, lane = channel)
    const float* vbase = vv + (size_t)bh * JDIM * DH;
    float oc = 0.f;
    const int jbeg = wave * (JDIM / 4);
    const int jend = (valid < jbeg + (JDIM / 4)) ? valid : (jbeg + (JDIM / 4));
    for (int j = jbeg; j < jend; ++j) oc += s[j] * vbase[(size_t)j * DH + lane];
    ored[wave][lane] = oc;
    __syncthreads();
    if (tid < DH) {
        float sum = (ored[0][tid] + ored[1][tid] + ored[2][tid] + ored[3][tid]) * rinv;
        const int b = bh >> 4;
        o[((size_t)b * T_DIM + i) * D_DIM + h * DH + tid] = sum;
    }
}

// ---------------------------------------------------------------------------
extern "C" void kernel_launch(void* const* d_in, const int* in_sizes, int n_in,
                              void* d_out, int out_size, void* d_ws, size_t ws_size,
                              hipStream_t stream) {
    const float* x = (const float*)d_in[0];
    const float* mem = (const float*)d_in[1];
    const float* wq = (const float*)d_in[2];
    const float* wkv = (const float*)d_in[3];
    const float* wo = (const float*)d_in[4];
    const float* bo = (const float*)d_in[5];
    const float* rel_w = (const float*)d_in[6];

    float* out = (float*)d_out;
    float* mem_next = out + (size_t)B_DIM * T_DIM * D_DIM;

    float* ws = (float*)d_ws;
    float* qh = ws;                    // 4*16*1024*64  = 4194304 floats
    float* kt = qh + 4194304;          // 4*16*2048*64  = 8388608 floats
    float* o = kt;                     // alias: kt dead after transpose
    float* kT = kt + 8388608;          // 8388608 floats
    float* v = kT + 8388608;           // 8388608 floats
    float* relT = v + 8388608;         // 16*64*2048    = 2097152 floats
    // total: 31457280 floats = 120 MB

    // mem_next = x
    hipLaunchKernelGGL(copy_kernel, dim3(4096), dim3(256), 0, stream, x, mem_next);

    // q = x @ wq -> head layout
    hipLaunchKernelGGL((gemm_tiled<0>), dim3(1024 / TILE, 4096 / TILE), dim3(256), 0,
                       stream, x, nullptr, wq, nullptr, qh, nullptr);

    // kv = [mem;x] @ wkv -> kt, v head layouts
    hipLaunchKernelGGL((gemm_tiled<1>), dim3(2048 / TILE, 8192 / TILE), dim3(256), 0,
                       stream, mem, x, wkv, nullptr, kt, v);

    // kT (bh,c,j) and relT (h,c,j')
    hipLaunchKernelGGL(transpose_k_kernel, dim3(JDIM / 32, DH / 32, B_DIM * H_DIM),
                       dim3(32, 8), 0, stream, kt, kT);
    hipLaunchKernelGGL(transpose_rel_kernel, dim3(JDIM / 32, DH / 32, H_DIM),
                       dim3(32, 8), 0, stream, rel_w, relT);

    // attention -> o (b, t, d) row-major (overwrites kt region; kt is dead)
    hipLaunchKernelGGL(attn_kernel, dim3(T_DIM, B_DIM * H_DIM), dim3(256), 0, stream,
                       qh, kT, v, relT, o);

    // out = o @ wo + bo
    hipLaunchKernelGGL((gemm_tiled<2>), dim3(1024 / TILE, 4096 / TILE), dim3(256), 0,
                       stream, o, nullptr, wo, bo, out, nullptr);
}

// Round 3
// 1062.391 us; speedup vs baseline: 10.1218x; 10.1218x over previous
//
#include <hip/hip_runtime.h>
#include <cstddef>
#include <cstdint>

#define B_DIM 4
#define T_DIM 1024
#define D_DIM 1024
#define H_DIM 16
#define DH 64
#define JDIM 2048
#define MEMLEN 1024
#define RELPAD 2176  // 2048 + 128 zero rows for banded-GEMM overrun

#define TILE 64
#define BK 16

typedef float floatx4 __attribute__((ext_vector_type(4)));
typedef short short8 __attribute__((ext_vector_type(8)));

static __device__ __forceinline__ short f2bf(float f) {
    union { float f; uint32_t u; } v; v.f = f;
    uint32_t r = (v.u + 0x7FFFu + ((v.u >> 16) & 1u)) >> 16;
    return (short)r;
}
static __device__ __forceinline__ float bf2f(short s) {
    union { uint32_t u; float f; } v; v.u = ((uint32_t)(unsigned short)s) << 16;
    return v.f;
}

// ---------------------------------------------------------------------------
// mem_next = x  (t == mem_len, concat([mem,x])[:, -1024:] == x)
// ---------------------------------------------------------------------------
__global__ __launch_bounds__(256) void copy_kernel(const float* __restrict__ src,
                                                   float* __restrict__ dst) {
    size_t idx = ((size_t)blockIdx.x * 256 + threadIdx.x) * 4;
    float4 v = *(const float4*)(src + idx);
    *(float4*)(dst + idx) = v;
}

// ---------------------------------------------------------------------------
// fp32 tiled GEMM, 64x64 tile, BK=16, 256 threads, 4x4 micro-tile per thread.
// MODE 0: q = x @ wq         -> qb bf16 [bh][i][c]
// MODE 1: kv = [mem;x]@wkv   -> kb bf16 [bh][j][c], vb fp32 [bh][j][c]
// MODE 2: out = o @ wo + bo  -> Cf fp32 row-major
// ---------------------------------------------------------------------------
template <int MODE>
__global__ __launch_bounds__(256) void gemm_tiled(
    const float* __restrict__ A0, const float* __restrict__ A1,
    const float* __restrict__ B, const float* __restrict__ bias,
    float* __restrict__ Cf, short* __restrict__ Cb, float* __restrict__ Cv) {
    constexpr int N = (MODE == 1) ? 2048 : 1024;
    constexpr int K = 1024;
    __shared__ float As[BK][TILE + 4];
    __shared__ float Bs[BK][TILE];

    const int tid = threadIdx.x;
    const int row0 = blockIdx.y * TILE;
    const int col0 = blockIdx.x * TILE;

    const int lm = tid >> 2;
    const int lk = (tid & 3) << 2;
    const int arow = row0 + lm;
    const float* aptr;
    if (MODE == 1) {
        int b = arow >> 11, jj = arow & 2047;
        aptr = (jj < MEMLEN) ? (A0 + ((size_t)b * MEMLEN + jj) * K)
                             : (A1 + ((size_t)b * T_DIM + (jj - MEMLEN)) * K);
    } else {
        aptr = A0 + (size_t)arow * K;
    }
    const int bk = tid >> 4;
    const int bn = (tid & 15) << 2;

    const int ty = tid >> 4, tx = tid & 15;
    float acc[4][4] = {};

    for (int k0 = 0; k0 < K; k0 += BK) {
        float4 av = *(const float4*)(aptr + k0 + lk);
        As[lk + 0][lm] = av.x;
        As[lk + 1][lm] = av.y;
        As[lk + 2][lm] = av.z;
        As[lk + 3][lm] = av.w;
        *(float4*)&Bs[bk][bn] = *(const float4*)(B + (size_t)(k0 + bk) * N + col0 + bn);
        __syncthreads();
#pragma unroll
        for (int kk = 0; kk < BK; ++kk) {
            float ar[4], br[4];
            *(float4*)ar = *(const float4*)&As[kk][ty << 2];
            *(float4*)br = *(const float4*)&Bs[kk][tx << 2];
#pragma unroll
            for (int ii = 0; ii < 4; ++ii)
#pragma unroll
                for (int jj = 0; jj < 4; ++jj) acc[ii][jj] += ar[ii] * br[jj];
        }
        __syncthreads();
    }

#pragma unroll
    for (int ii = 0; ii < 4; ++ii) {
        const int r = row0 + (ty << 2) + ii;
#pragma unroll
        for (int jj = 0; jj < 4; ++jj) {
            const int n = col0 + (tx << 2) + jj;
            const float val = acc[ii][jj];
            if (MODE == 0) {
                int b = r >> 10, i = r & 1023, h = n >> 6, c = n & 63;
                Cb[(((size_t)b * H_DIM + h) * T_DIM + i) * DH + c] = f2bf(val);
            } else if (MODE == 1) {
                int b = r >> 11, j = r & 2047;
                if (n < 1024) {
                    int h = n >> 6, c = n & 63;
                    Cb[(((size_t)b * H_DIM + h) * JDIM + j) * DH + c] = f2bf(val);
                } else {
                    int n2 = n - 1024, h = n2 >> 6, c = n2 & 63;
                    Cv[(((size_t)b * H_DIM + h) * JDIM + j) * DH + c] = val;
                }
            } else {
                Cf[(size_t)r * 1024 + n] = val + bias[n];
            }
        }
    }
}

// ---------------------------------------------------------------------------
// vb fp32 [bh][j][c] -> vTb bf16 [bh][c][j]
// ---------------------------------------------------------------------------
__global__ __launch_bounds__(256) void transpose_v(const float* __restrict__ vb,
                                                   short* __restrict__ vTb) {
    __shared__ float tile[32][33];
    const int bh = blockIdx.z;
    const int j0 = blockIdx.x * 32, c0 = blockIdx.y * 32;
    const int tx = threadIdx.x, ty = threadIdx.y;
    for (int r = ty; r < 32; r += 8)
        tile[r][tx] = vb[((size_t)bh * JDIM + j0 + r) * DH + c0 + tx];
    __syncthreads();
    for (int r = ty; r < 32; r += 8)
        vTb[((size_t)bh * DH + c0 + r) * JDIM + j0 + tx] = f2bf(tile[tx][r]);
}

// ---------------------------------------------------------------------------
// rel_w fp32 [jp][h][c] -> relb bf16 [h][jp][c], jp in [0,2176), zero pad tail
// ---------------------------------------------------------------------------
__global__ __launch_bounds__(256) void convert_rel(const float* __restrict__ rel,
                                                   short* __restrict__ relb) {
    const int h = blockIdx.y;
    const int jp = blockIdx.x * 16 + (threadIdx.x >> 4);
    const int c = (threadIdx.x & 15) << 2;
    float4 v = make_float4(0.f, 0.f, 0.f, 0.f);
    if (jp < JDIM) v = *(const float4*)(rel + ((size_t)jp * H_DIM + h) * DH + c);
    short4 o;
    o.x = f2bf(v.x); o.y = f2bf(v.y); o.z = f2bf(v.z); o.w = f2bf(v.w);
    *(short4*)(relb + ((size_t)h * RELPAD + jp) * DH + c) = o;
}

// ---------------------------------------------------------------------------
// Flash attention, bf16 MFMA 16x16x32. Block = (bh, 64-query i-tile), 4 waves,
// wave w owns rows [16w,16w+16). Per 64-j tile: QK^T MFMA + banded rel GEMM
// (G[v][u'] vs 128 staged rel rows, gather G[v][u-v+63]) + online softmax +
// PV MFMA. rel row for (i,j) is jp = j + 1023 - i; unmasked iff j <= i+1024.
// Staging: row = tid>>2 (64 rows), ch = (tid&3)*16 -> two float4 = 16 bf16,
// covering the full 64x64 tile (256 thr * 16 sh = 4096 sh).
// ---------------------------------------------------------------------------
__global__ __launch_bounds__(256) void flash_attn(
    const short* __restrict__ qb, const short* __restrict__ kb,
    const short* __restrict__ vTb, const short* __restrict__ relb,
    float* __restrict__ o) {
    __shared__ short ksh[64][72];     // K tile [j][c], +8 pad
    __shared__ short vsh[64][72];     // V tile [c][j]
    __shared__ short relsh[128][72];  // rel rows [u'][c]
    __shared__ short psh[64][72];     // P tile [i][j] (also Q staging at init)
    __shared__ short gsh[64][132];    // G [v][u'] bf16

    const int tid = threadIdx.x;
    const int w = tid >> 6;
    const int lane = tid & 63;
    const int l15 = lane & 15, quad = lane >> 4;
    const int bh = blockIdx.y, h = bh & 15, b = bh >> 4;
    const int i0 = blockIdx.x << 6;

    const int srow = tid >> 2;          // staging row 0..63
    const int sch = (tid & 3) << 4;     // staging col chunk: 16 shorts

    // stage Q (bf16) into psh, build A-fragments once
    {
        const short* qp = qb + ((size_t)bh * T_DIM + i0 + srow) * DH + sch;
        *(float4*)&psh[srow][sch] = *(const float4*)qp;
        *(float4*)&psh[srow][sch + 8] = *(const float4*)(qp + 8);
    }
    __syncthreads();
    short8 a_q0 = *(const short8*)&psh[(w << 4) + l15][quad << 3];
    short8 a_q1 = *(const short8*)&psh[(w << 4) + l15][32 + (quad << 3)];

    floatx4 o_acc[4] = {};  // [ct] col-tiles of output channels
    float m_r[4], l_r[4];
#pragma unroll
    for (int r = 0; r < 4; ++r) { m_r[r] = -3.0e38f; l_r[r] = 0.f; }

    const int jt_end = (i0 >> 6) + 17;  // covers j <= i0+63+1024
    const short* kb_b = kb + (size_t)bh * JDIM * DH;
    const short* vT_b = vTb + (size_t)bh * DH * JDIM;
    const short* rel_b = relb + (size_t)h * RELPAD * DH;

    for (int jt = 0; jt < jt_end; ++jt) {
        const int j0 = jt << 6;
        const int base0 = 960 + j0 - i0;  // rel row of G col u'=0; >=0, +127 < 2176

        __syncthreads();  // prev PV / psh reads done
        {
            const short* kp = kb_b + (size_t)(j0 + srow) * DH + sch;
            *(float4*)&ksh[srow][sch] = *(const float4*)kp;
            *(float4*)&ksh[srow][sch + 8] = *(const float4*)(kp + 8);
            const short* vp = vT_b + (size_t)srow * JDIM + j0 + sch;
            *(float4*)&vsh[srow][sch] = *(const float4*)vp;
            *(float4*)&vsh[srow][sch + 8] = *(const float4*)(vp + 8);
            const short* rp = rel_b + (size_t)(base0 + srow) * DH + sch;
            *(float4*)&relsh[srow][sch] = *(const float4*)rp;
            *(float4*)&relsh[srow][sch + 8] = *(const float4*)(rp + 8);
            const short* rp2 = rp + (size_t)64 * DH;
            *(float4*)&relsh[64 + srow][sch] = *(const float4*)rp2;
            *(float4*)&relsh[64 + srow][sch + 8] = *(const float4*)(rp2 + 8);
        }
        __syncthreads();  // stage visible

        // ---- QK^T ----
        floatx4 s_acc[4];
#pragma unroll
        for (int nt = 0; nt < 4; ++nt) {
            short8 bk0 = *(const short8*)&ksh[(nt << 4) + l15][quad << 3];
            short8 bk1 = *(const short8*)&ksh[(nt << 4) + l15][32 + (quad << 3)];
            floatx4 acc = {0.f, 0.f, 0.f, 0.f};
            acc = __builtin_amdgcn_mfma_f32_16x16x32_bf16(a_q0, bk0, acc, 0, 0, 0);
            acc = __builtin_amdgcn_mfma_f32_16x16x32_bf16(a_q1, bk1, acc, 0, 0, 0);
            s_acc[nt] = acc;
        }
        // ---- banded rel: G[v][u'] = q_v . rel[base0+u'] ----
#pragma unroll
        for (int nt = 0; nt < 8; ++nt) {
            short8 br0 = *(const short8*)&relsh[(nt << 4) + l15][quad << 3];
            short8 br1 = *(const short8*)&relsh[(nt << 4) + l15][32 + (quad << 3)];
            floatx4 acc = {0.f, 0.f, 0.f, 0.f};
            acc = __builtin_amdgcn_mfma_f32_16x16x32_bf16(a_q0, br0, acc, 0, 0, 0);
            acc = __builtin_amdgcn_mfma_f32_16x16x32_bf16(a_q1, br1, acc, 0, 0, 0);
#pragma unroll
            for (int r = 0; r < 4; ++r)
                gsh[(w << 4) + (quad << 2) + r][(nt << 4) + l15] = f2bf(acc[r]);
        }
        __syncthreads();  // gsh visible

        // ---- add shifted rel, mask, online softmax ----
        float tm[4] = {-3.0e38f, -3.0e38f, -3.0e38f, -3.0e38f};
#pragma unroll
        for (int nt = 0; nt < 4; ++nt) {
            const int u = (nt << 4) + l15;
            const int j = j0 + u;
#pragma unroll
            for (int r = 0; r < 4; ++r) {
                const int v = (w << 4) + (quad << 2) + r;
                const int i = i0 + v;
                float s = -3.0e38f;
                if (j <= i + MEMLEN)
                    s = (s_acc[nt][r] + bf2f(gsh[v][u - v + 63])) * 0.125f;
                s_acc[nt][r] = s;
                tm[r] = fmaxf(tm[r], s);
            }
        }
#pragma unroll
        for (int r = 0; r < 4; ++r) {
#pragma unroll
            for (int off = 1; off < 16; off <<= 1)
                tm[r] = fmaxf(tm[r], __shfl_xor(tm[r], off));
            const float mx = fmaxf(m_r[r], tm[r]);
            const float alpha = __expf(m_r[r] - mx);
            m_r[r] = mx;
            l_r[r] *= alpha;
#pragma unroll
            for (int ct = 0; ct < 4; ++ct) o_acc[ct][r] *= alpha;
            float rs = 0.f;
#pragma unroll
            for (int nt = 0; nt < 4; ++nt) {
                float p = __expf(s_acc[nt][r] - mx);
                rs += p;
                psh[(w << 4) + (quad << 2) + r][(nt << 4) + l15] = f2bf(p);
            }
#pragma unroll
            for (int off = 1; off < 16; off <<= 1) rs += __shfl_xor(rs, off);
            l_r[r] += rs;
        }
        __syncthreads();  // psh visible

        // ---- PV ----
        short8 a_p0 = *(const short8*)&psh[(w << 4) + l15][quad << 3];
        short8 a_p1 = *(const short8*)&psh[(w << 4) + l15][32 + (quad << 3)];
#pragma unroll
        for (int ct = 0; ct < 4; ++ct) {
            short8 bv0 = *(const short8*)&vsh[(ct << 4) + l15][quad << 3];
            short8 bv1 = *(const short8*)&vsh[(ct << 4) + l15][32 + (quad << 3)];
            o_acc[ct] = __builtin_amdgcn_mfma_f32_16x16x32_bf16(a_p0, bv0, o_acc[ct], 0, 0, 0);
            o_acc[ct] = __builtin_amdgcn_mfma_f32_16x16x32_bf16(a_p1, bv1, o_acc[ct], 0, 0, 0);
        }
    }

    // ---- epilogue: normalize, write o fp32 [b][i][d] ----
#pragma unroll
    for (int ct = 0; ct < 4; ++ct) {
#pragma unroll
        for (int r = 0; r < 4; ++r) {
            const int i = i0 + (w << 4) + (quad << 2) + r;
            const float val = o_acc[ct][r] / l_r[r];
            o[((size_t)b * T_DIM + i) * D_DIM + h * DH + (ct << 4) + l15] = val;
        }
    }
}

// ---------------------------------------------------------------------------
extern "C" void kernel_launch(void* const* d_in, const int* in_sizes, int n_in,
                              void* d_out, int out_size, void* d_ws, size_t ws_size,
                              hipStream_t stream) {
    const float* x = (const float*)d_in[0];
    const float* mem = (const float*)d_in[1];
    const float* wq = (const float*)d_in[2];
    const float* wkv = (const float*)d_in[3];
    const float* wo = (const float*)d_in[4];
    const float* bo = (const float*)d_in[5];
    const float* rel_w = (const float*)d_in[6];

    float* out = (float*)d_out;
    float* mem_next = out + (size_t)B_DIM * T_DIM * D_DIM;

    // workspace layout
    short* qb = (short*)d_ws;              // 4*16*1024*64           = 4,194,304 sh
    short* kb = qb + 4194304;              // 4*16*2048*64           = 8,388,608 sh
    short* vTb = kb + 8388608;             // 4*16*64*2048           = 8,388,608 sh
    short* relb = vTb + 8388608;           // 16*2176*64             = 2,228,224 sh
    float* vb = (float*)(relb + 2228224);  // 8,388,608 fp32 (32 MB)
    float* o = vb + 8388608;               // 4,194,304 fp32 (16 MB)

    // mem_next = x
    hipLaunchKernelGGL(copy_kernel, dim3(4096), dim3(256), 0, stream, x, mem_next);

    // q = x @ wq -> qb bf16
    hipLaunchKernelGGL((gemm_tiled<0>), dim3(16, 64), dim3(256), 0, stream,
                       x, nullptr, wq, nullptr, nullptr, qb, nullptr);

    // kv = [mem;x] @ wkv -> kb bf16, vb fp32
    hipLaunchKernelGGL((gemm_tiled<1>), dim3(32, 128), dim3(256), 0, stream,
                       mem, x, wkv, nullptr, nullptr, kb, vb);

    // vb -> vTb bf16 [bh][c][j]
    hipLaunchKernelGGL(transpose_v, dim3(JDIM / 32, DH / 32, B_DIM * H_DIM),
                       dim3(32, 8), 0, stream, vb, vTb);

    // rel_w -> relb bf16 [h][jp][c] (padded)
    hipLaunchKernelGGL(convert_rel, dim3(RELPAD / 16, H_DIM), dim3(256), 0, stream,
                       rel_w, relb);

    // flash attention -> o fp32 [b][i][d]
    hipLaunchKernelGGL(flash_attn, dim3(16, 64), dim3(256), 0, stream,
                       qb, kb, vTb, relb, o);

    // out = o @ wo + bo
    hipLaunchKernelGGL((gemm_tiled<2>), dim3(16, 64), dim3(256), 0, stream,
                       o, nullptr, wo, bo, out, nullptr, nullptr);
}

// Round 4
// 498.102 us; speedup vs baseline: 21.5885x; 2.1329x over previous
//
#include <hip/hip_runtime.h>
#include <cstddef>
#include <cstdint>

#define B_DIM 4
#define T_DIM 1024
#define D_DIM 1024
#define H_DIM 16
#define DH 64
#define JDIM 2048
#define MEMLEN 1024
#define RELPAD 2176  // 2048 + 128 zero rows for banded-GEMM overrun

typedef float floatx4 __attribute__((ext_vector_type(4)));
typedef short short8 __attribute__((ext_vector_type(8)));

static __device__ __forceinline__ short f2bf(float f) {
    union { float f; uint32_t u; } v; v.f = f;
    uint32_t r = (v.u + 0x7FFFu + ((v.u >> 16) & 1u)) >> 16;
    return (short)r;
}
static __device__ __forceinline__ float bf2f(short s) {
    union { uint32_t u; float f; } v; v.u = ((uint32_t)(unsigned short)s) << 16;
    return v.f;
}

// async global->LDS, 16B per lane; LDS dest = wave-uniform base + lane*16
static __device__ __forceinline__ void gl_lds16(const short* g, short* l) {
    __builtin_amdgcn_global_load_lds(
        (const __attribute__((address_space(1))) void*)g,
        (__attribute__((address_space(3))) void*)l, 16, 0, 0);
}

// ---------------------------------------------------------------------------
// mem_next = x  (t == mem_len, concat([mem,x])[:, -1024:] == x)
// ---------------------------------------------------------------------------
__global__ __launch_bounds__(256) void copy_kernel(const float* __restrict__ src,
                                                   float* __restrict__ dst) {
    size_t idx = ((size_t)blockIdx.x * 256 + threadIdx.x) * 4;
    float4 v = *(const float4*)(src + idx);
    *(float4*)(dst + idx) = v;
}

// ---------------------------------------------------------------------------
// kvb[b][j][d] bf16: j<1024 -> mem[b][j][d], else x[b][j-1024][d]
// ---------------------------------------------------------------------------
__global__ __launch_bounds__(256) void build_kv(const float* __restrict__ x,
                                                const float* __restrict__ mem,
                                                short* __restrict__ kvb) {
    const size_t idx = ((size_t)blockIdx.x * 256 + threadIdx.x) * 4;
    const int b = (int)(idx >> 21);
    const size_t r = idx & 2097151;  // j*1024 + d
    const float* src = (r < 1048576) ? (mem + (size_t)b * 1048576 + r)
                                     : (x + (size_t)b * 1048576 + (r - 1048576));
    float4 v = *(const float4*)src;
    short4 o;
    o.x = f2bf(v.x); o.y = f2bf(v.y); o.z = f2bf(v.z); o.w = f2bf(v.w);
    *(short4*)(kvb + idx) = o;
}

// ---------------------------------------------------------------------------
// wT[n][k] bf16 = w[k][n] fp32; grid (K/32, N/32), block (32,8)
// ---------------------------------------------------------------------------
__global__ __launch_bounds__(256) void transpose_w(const float* __restrict__ w,
                                                   short* __restrict__ wT,
                                                   int K, int N) {
    __shared__ float tile[32][33];
    const int k0 = blockIdx.x * 32, n0 = blockIdx.y * 32;
    const int tx = threadIdx.x, ty = threadIdx.y;
    for (int r = ty; r < 32; r += 8)
        tile[r][tx] = w[(size_t)(k0 + r) * N + n0 + tx];
    __syncthreads();
    for (int r = ty; r < 32; r += 8)
        wT[(size_t)(n0 + r) * K + k0 + tx] = f2bf(tile[tx][r]);
}

// ---------------------------------------------------------------------------
// rel_w fp32 [jp][h][c] -> relb bf16 [h][jp][c], jp in [0,2176), zero pad tail
// ---------------------------------------------------------------------------
__global__ __launch_bounds__(256) void convert_rel(const float* __restrict__ rel,
                                                   short* __restrict__ relb) {
    const int h = blockIdx.y;
    const int jp = blockIdx.x * 16 + (threadIdx.x >> 4);
    const int c = (threadIdx.x & 15) << 2;
    float4 v = make_float4(0.f, 0.f, 0.f, 0.f);
    if (jp < JDIM) v = *(const float4*)(rel + ((size_t)jp * H_DIM + h) * DH + c);
    short4 o;
    o.x = f2bf(v.x); o.y = f2bf(v.y); o.z = f2bf(v.z); o.w = f2bf(v.w);
    *(short4*)(relb + ((size_t)h * RELPAD + jp) * DH + c) = o;
}

// ---------------------------------------------------------------------------
// bf16 MFMA GEMM, 128x128 tile, BK=32, 256 threads (4 waves, 2x2 quadrants),
// global_load_lds width-16 staging, 16x16x32 MFMA, 4x4 tiles per wave.
// A: [M][1024] bf16 (AMODE 1 remaps row r -> kvb row of x). Bt: [N][1024].
// CMODE 0: -> qb [bh][i][c];  CMODE 1: n<1024 -> kb [bh][j][c],
//          n>=1024 -> vTb [bh][c][j];  CMODE 2: -> Cf fp32 [r][n] + bias.
// ---------------------------------------------------------------------------
template <int AMODE, int CMODE>
__global__ __launch_bounds__(256) void mfma_gemm(
    const short* __restrict__ A, const short* __restrict__ Bt,
    const float* __restrict__ bias,
    short* __restrict__ C0, short* __restrict__ C1, float* __restrict__ Cf) {
    constexpr int K = 1024;
    __shared__ short ash[128 * 32];
    __shared__ short bsh[128 * 32];

    const int tid = threadIdx.x;
    const int w = tid >> 6, lane = tid & 63;
    const int l15 = lane & 15, quad = lane >> 4;
    const int wr = w >> 1, wc = w & 1;
    const int row0 = blockIdx.y << 7, col0 = blockIdx.x << 7;

    // staging: wave w covers tile rows [w*32, w*32+32), 2 insts of 16 rows
    const int sk = (lane & 3) << 3;  // k offset in shorts (16B chunks)
    int tr0 = row0 + (w << 5) + (lane >> 2);
    int tr1 = tr0 + 16;
    if (AMODE == 1) {
        tr0 = ((tr0 >> 10) << 11) + 1024 + (tr0 & 1023);
        tr1 = ((tr1 >> 10) << 11) + 1024 + (tr1 & 1023);
    }
    const short* ap0 = A + (size_t)tr0 * K + sk;
    const short* ap1 = A + (size_t)tr1 * K + sk;
    const short* bp0 = Bt + (size_t)(col0 + (w << 5) + (lane >> 2)) * K + sk;
    const short* bp1 = bp0 + (size_t)16 * K;

    floatx4 acc[4][4] = {};

    for (int k0 = 0; k0 < K; k0 += 32) {
        __syncthreads();  // prev ds_reads done before overwrite
        gl_lds16(ap0 + k0, ash + (w << 10));
        gl_lds16(ap1 + k0, ash + (w << 10) + 512);
        gl_lds16(bp0 + k0, bsh + (w << 10));
        gl_lds16(bp1 + k0, bsh + (w << 10) + 512);
        __syncthreads();  // stage visible (vmcnt drained at barrier)

        short8 af[4];
#pragma unroll
        for (int mt = 0; mt < 4; ++mt)
            af[mt] = *(const short8*)&ash[(((wr << 6) + (mt << 4) + l15) << 5) + (quad << 3)];
#pragma unroll
        for (int nt = 0; nt < 4; ++nt) {
            short8 bf = *(const short8*)&bsh[(((wc << 6) + (nt << 4) + l15) << 5) + (quad << 3)];
#pragma unroll
            for (int mt = 0; mt < 4; ++mt)
                acc[mt][nt] = __builtin_amdgcn_mfma_f32_16x16x32_bf16(af[mt], bf, acc[mt][nt], 0, 0, 0);
        }
    }

#pragma unroll
    for (int nt = 0; nt < 4; ++nt) {
        const int col = col0 + (wc << 6) + (nt << 4) + l15;
        float bv = (CMODE == 2) ? bias[col] : 0.f;
#pragma unroll
        for (int mt = 0; mt < 4; ++mt) {
#pragma unroll
            for (int rr = 0; rr < 4; ++rr) {
                const int row = row0 + (wr << 6) + (mt << 4) + (quad << 2) + rr;
                const float val = acc[mt][nt][rr];
                if (CMODE == 0) {
                    int b = row >> 10, i = row & 1023, h = col >> 6, c = col & 63;
                    C0[(((size_t)b * H_DIM + h) * T_DIM + i) * DH + c] = f2bf(val);
                } else if (CMODE == 1) {
                    int b = row >> 11, j = row & 2047;
                    if (col < 1024) {
                        int h = col >> 6, c = col & 63;
                        C0[(((size_t)b * H_DIM + h) * JDIM + j) * DH + c] = f2bf(val);
                    } else {
                        int n2 = col - 1024, h = n2 >> 6, c = n2 & 63;
                        C1[(((size_t)b * H_DIM + h) * DH + c) * JDIM + j] = f2bf(val);
                    }
                } else {
                    Cf[(size_t)row * 1024 + col] = val + bv;
                }
            }
        }
    }
}

// ---------------------------------------------------------------------------
// Flash attention, bf16 MFMA 16x16x32. Block = (bh, 64-query i-tile), 4 waves,
// wave w owns rows [16w,16w+16). Per 64-j tile: QK^T MFMA + banded rel GEMM
// (G[v][u'] vs 128 staged rel rows, gather G[v][u-v+63]) + online softmax +
// PV MFMA. rel row for (i,j) is jp = j + 1023 - i; unmasked iff j <= i+1024.
// ---------------------------------------------------------------------------
__global__ __launch_bounds__(256) void flash_attn(
    const short* __restrict__ qb, const short* __restrict__ kb,
    const short* __restrict__ vTb, const short* __restrict__ relb,
    short* __restrict__ ob) {
    __shared__ short ksh[64][72];     // K tile [j][c], +8 pad
    __shared__ short vsh[64][72];     // V tile [c][j]
    __shared__ short relsh[128][72];  // rel rows [u'][c]
    __shared__ short psh[64][72];     // P tile [i][j] (also Q staging at init)
    __shared__ short gsh[64][132];    // G [v][u'] bf16

    const int tid = threadIdx.x;
    const int w = tid >> 6;
    const int lane = tid & 63;
    const int l15 = lane & 15, quad = lane >> 4;
    const int bh = blockIdx.y, h = bh & 15, b = bh >> 4;
    const int i0 = blockIdx.x << 6;

    const int srow = tid >> 2;       // staging row 0..63
    const int sch = (tid & 3) << 4;  // staging col chunk: 16 shorts

    // stage Q (bf16) into psh, build A-fragments once
    {
        const short* qp = qb + ((size_t)bh * T_DIM + i0 + srow) * DH + sch;
        *(float4*)&psh[srow][sch] = *(const float4*)qp;
        *(float4*)&psh[srow][sch + 8] = *(const float4*)(qp + 8);
    }
    __syncthreads();
    short8 a_q0 = *(const short8*)&psh[(w << 4) + l15][quad << 3];
    short8 a_q1 = *(const short8*)&psh[(w << 4) + l15][32 + (quad << 3)];

    floatx4 o_acc[4] = {};  // [ct] col-tiles of output channels
    float m_r[4], l_r[4];
#pragma unroll
    for (int r = 0; r < 4; ++r) { m_r[r] = -3.0e38f; l_r[r] = 0.f; }

    const int jt_end = (i0 >> 6) + 17;  // covers j <= i0+63+1024
    const short* kb_b = kb + (size_t)bh * JDIM * DH;
    const short* vT_b = vTb + (size_t)bh * DH * JDIM;
    const short* rel_b = relb + (size_t)h * RELPAD * DH;

    for (int jt = 0; jt < jt_end; ++jt) {
        const int j0 = jt << 6;
        const int base0 = 960 + j0 - i0;  // rel row of G col u'=0; >=0, +127 < 2176

        __syncthreads();  // prev PV / psh reads done
        {
            const short* kp = kb_b + (size_t)(j0 + srow) * DH + sch;
            *(float4*)&ksh[srow][sch] = *(const float4*)kp;
            *(float4*)&ksh[srow][sch + 8] = *(const float4*)(kp + 8);
            const short* vp = vT_b + (size_t)srow * JDIM + j0 + sch;
            *(float4*)&vsh[srow][sch] = *(const float4*)vp;
            *(float4*)&vsh[srow][sch + 8] = *(const float4*)(vp + 8);
            const short* rp = rel_b + (size_t)(base0 + srow) * DH + sch;
            *(float4*)&relsh[srow][sch] = *(const float4*)rp;
            *(float4*)&relsh[srow][sch + 8] = *(const float4*)(rp + 8);
            const short* rp2 = rp + (size_t)64 * DH;
            *(float4*)&relsh[64 + srow][sch] = *(const float4*)rp2;
            *(float4*)&relsh[64 + srow][sch + 8] = *(const float4*)(rp2 + 8);
        }
        __syncthreads();  // stage visible

        // ---- QK^T ----
        floatx4 s_acc[4];
#pragma unroll
        for (int nt = 0; nt < 4; ++nt) {
            short8 bk0 = *(const short8*)&ksh[(nt << 4) + l15][quad << 3];
            short8 bk1 = *(const short8*)&ksh[(nt << 4) + l15][32 + (quad << 3)];
            floatx4 acc = {0.f, 0.f, 0.f, 0.f};
            acc = __builtin_amdgcn_mfma_f32_16x16x32_bf16(a_q0, bk0, acc, 0, 0, 0);
            acc = __builtin_amdgcn_mfma_f32_16x16x32_bf16(a_q1, bk1, acc, 0, 0, 0);
            s_acc[nt] = acc;
        }
        // ---- banded rel: G[v][u'] = q_v . rel[base0+u'] ----
#pragma unroll
        for (int nt = 0; nt < 8; ++nt) {
            short8 br0 = *(const short8*)&relsh[(nt << 4) + l15][quad << 3];
            short8 br1 = *(const short8*)&relsh[(nt << 4) + l15][32 + (quad << 3)];
            floatx4 acc = {0.f, 0.f, 0.f, 0.f};
            acc = __builtin_amdgcn_mfma_f32_16x16x32_bf16(a_q0, br0, acc, 0, 0, 0);
            acc = __builtin_amdgcn_mfma_f32_16x16x32_bf16(a_q1, br1, acc, 0, 0, 0);
#pragma unroll
            for (int r = 0; r < 4; ++r)
                gsh[(w << 4) + (quad << 2) + r][(nt << 4) + l15] = f2bf(acc[r]);
        }
        __syncthreads();  // gsh visible

        // ---- add shifted rel, mask, online softmax ----
        float tm[4] = {-3.0e38f, -3.0e38f, -3.0e38f, -3.0e38f};
#pragma unroll
        for (int nt = 0; nt < 4; ++nt) {
            const int u = (nt << 4) + l15;
            const int j = j0 + u;
#pragma unroll
            for (int r = 0; r < 4; ++r) {
                const int v = (w << 4) + (quad << 2) + r;
                const int i = i0 + v;
                float s = -3.0e38f;
                if (j <= i + MEMLEN)
                    s = (s_acc[nt][r] + bf2f(gsh[v][u - v + 63])) * 0.125f;
                s_acc[nt][r] = s;
                tm[r] = fmaxf(tm[r], s);
            }
        }
#pragma unroll
        for (int r = 0; r < 4; ++r) {
#pragma unroll
            for (int off = 1; off < 16; off <<= 1)
                tm[r] = fmaxf(tm[r], __shfl_xor(tm[r], off));
            const float mx = fmaxf(m_r[r], tm[r]);
            const float alpha = __expf(m_r[r] - mx);
            m_r[r] = mx;
            l_r[r] *= alpha;
#pragma unroll
            for (int ct = 0; ct < 4; ++ct) o_acc[ct][r] *= alpha;
            float rs = 0.f;
#pragma unroll
            for (int nt = 0; nt < 4; ++nt) {
                float p = __expf(s_acc[nt][r] - mx);
                rs += p;
                psh[(w << 4) + (quad << 2) + r][(nt << 4) + l15] = f2bf(p);
            }
#pragma unroll
            for (int off = 1; off < 16; off <<= 1) rs += __shfl_xor(rs, off);
            l_r[r] += rs;
        }
        __syncthreads();  // psh visible

        // ---- PV ----
        short8 a_p0 = *(const short8*)&psh[(w << 4) + l15][quad << 3];
        short8 a_p1 = *(const short8*)&psh[(w << 4) + l15][32 + (quad << 3)];
#pragma unroll
        for (int ct = 0; ct < 4; ++ct) {
            short8 bv0 = *(const short8*)&vsh[(ct << 4) + l15][quad << 3];
            short8 bv1 = *(const short8*)&vsh[(ct << 4) + l15][32 + (quad << 3)];
            o_acc[ct] = __builtin_amdgcn_mfma_f32_16x16x32_bf16(a_p0, bv0, o_acc[ct], 0, 0, 0);
            o_acc[ct] = __builtin_amdgcn_mfma_f32_16x16x32_bf16(a_p1, bv1, o_acc[ct], 0, 0, 0);
        }
    }

    // ---- epilogue: normalize, write ob bf16 [b][i][d] ----
#pragma unroll
    for (int ct = 0; ct < 4; ++ct) {
#pragma unroll
        for (int r = 0; r < 4; ++r) {
            const int i = i0 + (w << 4) + (quad << 2) + r;
            const float val = o_acc[ct][r] / l_r[r];
            ob[((size_t)b * T_DIM + i) * D_DIM + h * DH + (ct << 4) + l15] = f2bf(val);
        }
    }
}

// ---------------------------------------------------------------------------
extern "C" void kernel_launch(void* const* d_in, const int* in_sizes, int n_in,
                              void* d_out, int out_size, void* d_ws, size_t ws_size,
                              hipStream_t stream) {
    const float* x = (const float*)d_in[0];
    const float* mem = (const float*)d_in[1];
    const float* wq = (const float*)d_in[2];
    const float* wkv = (const float*)d_in[3];
    const float* wo = (const float*)d_in[4];
    const float* bo = (const float*)d_in[5];
    const float* rel_w = (const float*)d_in[6];

    float* out = (float*)d_out;
    float* mem_next = out + (size_t)B_DIM * T_DIM * D_DIM;

    // workspace layout (shorts), ~80 MB total
    short* kvb = (short*)d_ws;       // 8,388,608  [b][j][d] bf16
    short* qb = kvb + 8388608;       // 4,194,304  [bh][i][c]
    short* kb = qb + 4194304;        // 8,388,608  [bh][j][c]
    short* vTb = kb + 8388608;       // 8,388,608  [bh][c][j]
    short* relb = vTb + 8388608;     // 2,228,224  [h][jp][c]
    short* ob = relb + 2228224;      // 4,194,304  [b*i][d]
    short* wqT = ob + 4194304;       // 1,048,576  [n][k]
    short* wkvT = wqT + 1048576;     // 2,097,152  [n][k]
    short* woT = wkvT + 2097152;     // 1,048,576  [n][k]

    // mem_next = x
    hipLaunchKernelGGL(copy_kernel, dim3(4096), dim3(256), 0, stream, x, mem_next);

    // kvb = bf16(concat(mem, x))
    hipLaunchKernelGGL(build_kv, dim3(8192), dim3(256), 0, stream, x, mem, kvb);

    // weight transposes -> bf16 [n][k]
    hipLaunchKernelGGL(transpose_w, dim3(32, 32), dim3(32, 8), 0, stream, wq, wqT, 1024, 1024);
    hipLaunchKernelGGL(transpose_w, dim3(32, 64), dim3(32, 8), 0, stream, wkv, wkvT, 1024, 2048);
    hipLaunchKernelGGL(transpose_w, dim3(32, 32), dim3(32, 8), 0, stream, wo, woT, 1024, 1024);

    // rel_w -> relb bf16 [h][jp][c] (padded)
    hipLaunchKernelGGL(convert_rel, dim3(RELPAD / 16, H_DIM), dim3(256), 0, stream,
                       rel_w, relb);

    // q = x @ wq -> qb   (A rows remapped into kvb's x-half)
    hipLaunchKernelGGL((mfma_gemm<1, 0>), dim3(8, 32), dim3(256), 0, stream,
                       kvb, wqT, nullptr, qb, nullptr, nullptr);

    // kv = kvin @ wkv -> kb, vTb
    hipLaunchKernelGGL((mfma_gemm<0, 1>), dim3(16, 64), dim3(256), 0, stream,
                       kvb, wkvT, nullptr, kb, vTb, nullptr);

    // flash attention -> ob bf16
    hipLaunchKernelGGL(flash_attn, dim3(16, 64), dim3(256), 0, stream,
                       qb, kb, vTb, relb, ob);

    // out = ob @ wo + bo -> fp32
    hipLaunchKernelGGL((mfma_gemm<0, 2>), dim3(8, 32), dim3(256), 0, stream,
                       ob, woT, bo, nullptr, nullptr, out);
}

// Round 5
// 468.469 us; speedup vs baseline: 22.9541x; 1.0633x over previous
//
#include <hip/hip_runtime.h>
#include <cstddef>
#include <cstdint>

#define B_DIM 4
#define T_DIM 1024
#define D_DIM 1024
#define H_DIM 16
#define DH 64
#define JDIM 2048
#define MEMLEN 1024
#define RELPAD 2176  // 2048 + 128 zero rows for banded-GEMM overrun

typedef float floatx4 __attribute__((ext_vector_type(4)));
typedef short short8 __attribute__((ext_vector_type(8)));

static __device__ __forceinline__ short f2bf(float f) {
    union { float f; uint32_t u; } v; v.f = f;
    uint32_t r = (v.u + 0x7FFFu + ((v.u >> 16) & 1u)) >> 16;
    return (short)r;
}

// async global->LDS, 16B per lane; LDS dest = wave-uniform base + lane*16
static __device__ __forceinline__ void gl_lds16(const short* g, short* l) {
    __builtin_amdgcn_global_load_lds(
        (const __attribute__((address_space(1))) void*)g,
        (__attribute__((address_space(3))) void*)l, 16, 0, 0);
}

// ---------------------------------------------------------------------------
// Fused: mem_next = x; kvb = bf16(concat(mem, x)).
// Blocks 0..4095 handle x (write mem_next + kvb x-half); 4096..8191 handle mem.
// ---------------------------------------------------------------------------
__global__ __launch_bounds__(256) void prep_xmem(const float* __restrict__ x,
                                                 const float* __restrict__ mem,
                                                 float* __restrict__ mem_next,
                                                 short* __restrict__ kvb) {
    const size_t gid = (size_t)blockIdx.x * 256 + threadIdx.x;
    if (gid < 1048576) {
        const size_t idx = gid * 4;
        float4 v = *(const float4*)(x + idx);
        *(float4*)(mem_next + idx) = v;
        const int b = (int)(idx >> 20);
        const size_t r = idx & 1048575;
        short4 o;
        o.x = f2bf(v.x); o.y = f2bf(v.y); o.z = f2bf(v.z); o.w = f2bf(v.w);
        *(short4*)(kvb + (size_t)b * 2097152 + 1048576 + r) = o;
    } else {
        const size_t idx = (gid - 1048576) * 4;
        float4 v = *(const float4*)(mem + idx);
        const int b = (int)(idx >> 20);
        const size_t r = idx & 1048575;
        short4 o;
        o.x = f2bf(v.x); o.y = f2bf(v.y); o.z = f2bf(v.z); o.w = f2bf(v.w);
        *(short4*)(kvb + (size_t)b * 2097152 + r) = o;
    }
}

// ---------------------------------------------------------------------------
// All 3 weight transposes in one launch. z=0: wq, z=1: wkv, z=2: wo.
// wT[n][k] bf16 = w[k][n] fp32.
// ---------------------------------------------------------------------------
__global__ __launch_bounds__(256) void transpose_w3(
    const float* __restrict__ wq, const float* __restrict__ wkv,
    const float* __restrict__ wo, short* __restrict__ wqT,
    short* __restrict__ wkvT, short* __restrict__ woT) {
    const int z = blockIdx.z;
    const int N = (z == 1) ? 2048 : 1024;
    if (blockIdx.y * 32 >= N) return;
    const float* w = (z == 0) ? wq : (z == 1) ? wkv : wo;
    short* wT = (z == 0) ? wqT : (z == 1) ? wkvT : woT;
    __shared__ float tile[32][33];
    const int k0 = blockIdx.x * 32, n0 = blockIdx.y * 32;
    const int tx = threadIdx.x, ty = threadIdx.y;
    for (int r = ty; r < 32; r += 8)
        tile[r][tx] = w[(size_t)(k0 + r) * N + n0 + tx];
    __syncthreads();
    for (int r = ty; r < 32; r += 8)
        wT[(size_t)(n0 + r) * 1024 + k0 + tx] = f2bf(tile[tx][r]);
}

// ---------------------------------------------------------------------------
// rel_w fp32 [jp][h][c] -> relb bf16 [h][jp][c], jp in [0,2176), zero pad tail
// ---------------------------------------------------------------------------
__global__ __launch_bounds__(256) void convert_rel(const float* __restrict__ rel,
                                                   short* __restrict__ relb) {
    const int h = blockIdx.y;
    const int jp = blockIdx.x * 16 + (threadIdx.x >> 4);
    const int c = (threadIdx.x & 15) << 2;
    float4 v = make_float4(0.f, 0.f, 0.f, 0.f);
    if (jp < JDIM) v = *(const float4*)(rel + ((size_t)jp * H_DIM + h) * DH + c);
    short4 o;
    o.x = f2bf(v.x); o.y = f2bf(v.y); o.z = f2bf(v.z); o.w = f2bf(v.w);
    *(short4*)(relb + ((size_t)h * RELPAD + jp) * DH + c) = o;
}

// ---------------------------------------------------------------------------
// bf16 MFMA GEMM, 128x128 tile, BK=32, 256 threads (4 waves, 2x2 quadrants),
// global_load_lds width-16 staging, 16x16x32 MFMA, 4x4 tiles per wave.
// A: [M][1024] bf16 (AMODE 1 remaps row r -> kvb row of x). Bt: [N][1024].
// CMODE 0: -> qb [bh][i][c];  CMODE 1: n<1024 -> kb [bh][j][c],
//          n>=1024 -> vTb [bh][c][j];  CMODE 2: -> Cf fp32 [r][n] + bias.
// ---------------------------------------------------------------------------
template <int AMODE, int CMODE>
__global__ __launch_bounds__(256) void mfma_gemm(
    const short* __restrict__ A, const short* __restrict__ Bt,
    const float* __restrict__ bias,
    short* __restrict__ C0, short* __restrict__ C1, float* __restrict__ Cf) {
    constexpr int K = 1024;
    __shared__ short ash[128 * 32];
    __shared__ short bsh[128 * 32];

    const int tid = threadIdx.x;
    const int w = tid >> 6, lane = tid & 63;
    const int l15 = lane & 15, quad = lane >> 4;
    const int wr = w >> 1, wc = w & 1;
    const int row0 = blockIdx.y << 7, col0 = blockIdx.x << 7;

    const int sk = (lane & 3) << 3;
    int tr0 = row0 + (w << 5) + (lane >> 2);
    int tr1 = tr0 + 16;
    if (AMODE == 1) {
        tr0 = ((tr0 >> 10) << 11) + 1024 + (tr0 & 1023);
        tr1 = ((tr1 >> 10) << 11) + 1024 + (tr1 & 1023);
    }
    const short* ap0 = A + (size_t)tr0 * K + sk;
    const short* ap1 = A + (size_t)tr1 * K + sk;
    const short* bp0 = Bt + (size_t)(col0 + (w << 5) + (lane >> 2)) * K + sk;
    const short* bp1 = bp0 + (size_t)16 * K;

    floatx4 acc[4][4] = {};

    for (int k0 = 0; k0 < K; k0 += 32) {
        __syncthreads();
        gl_lds16(ap0 + k0, ash + (w << 10));
        gl_lds16(ap1 + k0, ash + (w << 10) + 512);
        gl_lds16(bp0 + k0, bsh + (w << 10));
        gl_lds16(bp1 + k0, bsh + (w << 10) + 512);
        __syncthreads();

        short8 af[4];
#pragma unroll
        for (int mt = 0; mt < 4; ++mt)
            af[mt] = *(const short8*)&ash[(((wr << 6) + (mt << 4) + l15) << 5) + (quad << 3)];
#pragma unroll
        for (int nt = 0; nt < 4; ++nt) {
            short8 bf = *(const short8*)&bsh[(((wc << 6) + (nt << 4) + l15) << 5) + (quad << 3)];
#pragma unroll
            for (int mt = 0; mt < 4; ++mt)
                acc[mt][nt] = __builtin_amdgcn_mfma_f32_16x16x32_bf16(af[mt], bf, acc[mt][nt], 0, 0, 0);
        }
    }

#pragma unroll
    for (int nt = 0; nt < 4; ++nt) {
        const int col = col0 + (wc << 6) + (nt << 4) + l15;
        float bv = (CMODE == 2) ? bias[col] : 0.f;
#pragma unroll
        for (int mt = 0; mt < 4; ++mt) {
#pragma unroll
            for (int rr = 0; rr < 4; ++rr) {
                const int row = row0 + (wr << 6) + (mt << 4) + (quad << 2) + rr;
                const float val = acc[mt][nt][rr];
                if (CMODE == 0) {
                    int b = row >> 10, i = row & 1023, h = col >> 6, c = col & 63;
                    C0[(((size_t)b * H_DIM + h) * T_DIM + i) * DH + c] = f2bf(val);
                } else if (CMODE == 1) {
                    int b = row >> 11, j = row & 2047;
                    if (col < 1024) {
                        int h = col >> 6, c = col & 63;
                        C0[(((size_t)b * H_DIM + h) * JDIM + j) * DH + c] = f2bf(val);
                    } else {
                        int n2 = col - 1024, h = n2 >> 6, c = n2 & 63;
                        C1[(((size_t)b * H_DIM + h) * DH + c) * JDIM + j] = f2bf(val);
                    }
                } else {
                    Cf[(size_t)row * 1024 + col] = val + bv;
                }
            }
        }
    }
}

// ---------------------------------------------------------------------------
// Flash attention v2. Block = (bh, 64-query i-tile), 4 waves, wave w owns
// rows [16w,16w+16). Per 64-j tile:
//   QK^T (8 MFMA) + banded rel G (10 MFMA: only blocks 3-w..7-w are in wave
//   w's band) -> shuffle-gather G[m][u-v+63] in-wave (src lane (quad, t&15),
//   reg select t>>4; t = l15-4q-r+15) -> exp2-domain online softmax ->
//   P round-trip through wave-private psh (no barrier) -> PV (8 MFMA) +
//   row-sum l via 2 ones-MFMAs. Mask only on the last j-tile (u <= v there).
// LDS 45 KB -> 3 blocks/CU. 2 barriers per iteration.
// ---------------------------------------------------------------------------
__global__ __launch_bounds__(256, 3) void flash_attn(
    const short* __restrict__ qb, const short* __restrict__ kb,
    const short* __restrict__ vTb, const short* __restrict__ relb,
    short* __restrict__ ob) {
    __shared__ short ksh[64][72];     // K tile [j][c]
    __shared__ short vsh[64][72];     // V tile [c][j]
    __shared__ short relsh[128][72];  // rel rows [u'][c]
    __shared__ short psh[64][72];     // P tile [i][j], wave-private rows

    const int tid = threadIdx.x;
    const int w = tid >> 6;
    const int lane = tid & 63;
    const int l15 = lane & 15, quad = lane >> 4;
    const int bh = blockIdx.y, h = bh & 15, b = bh >> 4;
    const int i0 = blockIdx.x << 6;
    const int goff = 3 - w;

    const int srow = tid >> 2;       // staging row 0..63
    const int sch = (tid & 3) << 4;  // staging col chunk: 16 shorts

    // stage Q (bf16) into psh (wave-private rows), build A-fragments once
    {
        const short* qp = qb + ((size_t)bh * T_DIM + i0 + srow) * DH + sch;
        *(float4*)&psh[srow][sch] = *(const float4*)qp;
        *(float4*)&psh[srow][sch + 8] = *(const float4*)(qp + 8);
    }
    __syncthreads();
    const short8 a_q0 = *(const short8*)&psh[(w << 4) + l15][quad << 3];
    const short8 a_q1 = *(const short8*)&psh[(w << 4) + l15][32 + (quad << 3)];

    // all-ones B fragment for row-sum MFMA
    short8 ones8;
#pragma unroll
    for (int z = 0; z < 8; ++z) ones8[z] = (short)0x3F80;

    // hoisted gather controls: per target reg r, source lane & register select
    int srcl[4], gsel[4];
#pragma unroll
    for (int r = 0; r < 4; ++r) {
        const int t = l15 - (quad << 2) - r + 15;  // in [0,30]
        gsel[r] = t >> 4;
        srcl[r] = (quad << 4) | (t & 15);
    }

    floatx4 o_acc[4] = {};
    float m_r[4], l_r[4];
#pragma unroll
    for (int r = 0; r < 4; ++r) { m_r[r] = -3.0e38f; l_r[r] = 0.f; }

    const int jt_end = (i0 >> 6) + 17;
    const short* kb_b = kb + (size_t)bh * JDIM * DH;
    const short* vT_b = vTb + (size_t)bh * DH * JDIM;
    const short* rel_b = relb + (size_t)h * RELPAD * DH;
    const float SC = 0.18033688f;  // 0.125 * log2(e)

    for (int jt = 0; jt < jt_end; ++jt) {
        const int j0 = jt << 6;
        const int base0 = 960 + j0 - i0;  // in [0, 1984]

        __syncthreads();  // all waves done reading prev ksh/vsh/relsh
        {
            const short* kp = kb_b + (size_t)(j0 + srow) * DH + sch;
            *(float4*)&ksh[srow][sch] = *(const float4*)kp;
            *(float4*)&ksh[srow][sch + 8] = *(const float4*)(kp + 8);
            const short* vp = vT_b + (size_t)srow * JDIM + j0 + sch;
            *(float4*)&vsh[srow][sch] = *(const float4*)vp;
            *(float4*)&vsh[srow][sch + 8] = *(const float4*)(vp + 8);
            const short* rp = rel_b + (size_t)(base0 + srow) * DH + sch;
            *(float4*)&relsh[srow][sch] = *(const float4*)rp;
            *(float4*)&relsh[srow][sch + 8] = *(const float4*)(rp + 8);
            const short* rp2 = rp + (size_t)64 * DH;
            *(float4*)&relsh[64 + srow][sch] = *(const float4*)rp2;
            *(float4*)&relsh[64 + srow][sch + 8] = *(const float4*)(rp2 + 8);
        }
        __syncthreads();  // stage visible

        // ---- QK^T ----
        floatx4 s_acc[4];
#pragma unroll
        for (int nt = 0; nt < 4; ++nt) {
            short8 bk0 = *(const short8*)&ksh[(nt << 4) + l15][quad << 3];
            short8 bk1 = *(const short8*)&ksh[(nt << 4) + l15][32 + (quad << 3)];
            floatx4 acc = {0.f, 0.f, 0.f, 0.f};
            acc = __builtin_amdgcn_mfma_f32_16x16x32_bf16(a_q0, bk0, acc, 0, 0, 0);
            acc = __builtin_amdgcn_mfma_f32_16x16x32_bf16(a_q1, bk1, acc, 0, 0, 0);
            s_acc[nt] = acc;
        }

        // ---- banded rel: only G blocks gi+goff, gi in [0,5) ----
        floatx4 G[5];
#pragma unroll
        for (int gi = 0; gi < 5; ++gi) {
            const int rrow = ((gi + goff) << 4) + l15;
            short8 br0 = *(const short8*)&relsh[rrow][quad << 3];
            short8 br1 = *(const short8*)&relsh[rrow][32 + (quad << 3)];
            floatx4 acc = {0.f, 0.f, 0.f, 0.f};
            acc = __builtin_amdgcn_mfma_f32_16x16x32_bf16(a_q0, br0, acc, 0, 0, 0);
            G[gi] = __builtin_amdgcn_mfma_f32_16x16x32_bf16(a_q1, br1, acc, 0, 0, 0);
        }

        // ---- shuffle-gather shifted rel, combine (exp2 domain) ----
#pragma unroll
        for (int nt = 0; nt < 4; ++nt) {
#pragma unroll
            for (int r = 0; r < 4; ++r) {
                const float ga = __shfl(G[nt][r], srcl[r], 64);
                const float gb = __shfl(G[nt + 1][r], srcl[r], 64);
                const float g = gsel[r] ? gb : ga;
                s_acc[nt][r] = (s_acc[nt][r] + g) * SC;
            }
        }
        if (jt == jt_end - 1) {  // triangular mask: valid iff u <= v
#pragma unroll
            for (int nt = 0; nt < 4; ++nt) {
                const int u = (nt << 4) + l15;
#pragma unroll
                for (int r = 0; r < 4; ++r) {
                    const int v = (w << 4) + (quad << 2) + r;
                    if (u > v) s_acc[nt][r] = -3.0e38f;
                }
            }
        }

        // ---- online softmax ----
        float tm[4] = {-3.0e38f, -3.0e38f, -3.0e38f, -3.0e38f};
#pragma unroll
        for (int nt = 0; nt < 4; ++nt)
#pragma unroll
            for (int r = 0; r < 4; ++r) tm[r] = fmaxf(tm[r], s_acc[nt][r]);
#pragma unroll
        for (int r = 0; r < 4; ++r) {
#pragma unroll
            for (int off = 1; off < 16; off <<= 1)
                tm[r] = fmaxf(tm[r], __shfl_xor(tm[r], off));
            const float mx = fmaxf(m_r[r], tm[r]);
            const float alpha = exp2f(m_r[r] - mx);
            m_r[r] = mx;
            l_r[r] *= alpha;
#pragma unroll
            for (int ct = 0; ct < 4; ++ct) o_acc[ct][r] *= alpha;
#pragma unroll
            for (int nt = 0; nt < 4; ++nt) {
                const float p = exp2f(s_acc[nt][r] - mx);
                psh[(w << 4) + (quad << 2) + r][(nt << 4) + l15] = f2bf(p);
            }
        }
        // no barrier: psh rows are wave-private

        // ---- PV + row-sum ----
        const short8 a_p0 = *(const short8*)&psh[(w << 4) + l15][quad << 3];
        const short8 a_p1 = *(const short8*)&psh[(w << 4) + l15][32 + (quad << 3)];
        floatx4 ls = {0.f, 0.f, 0.f, 0.f};
        ls = __builtin_amdgcn_mfma_f32_16x16x32_bf16(a_p0, ones8, ls, 0, 0, 0);
        ls = __builtin_amdgcn_mfma_f32_16x16x32_bf16(a_p1, ones8, ls, 0, 0, 0);
#pragma unroll
        for (int r = 0; r < 4; ++r) l_r[r] += ls[r];
#pragma unroll
        for (int ct = 0; ct < 4; ++ct) {
            short8 bv0 = *(const short8*)&vsh[(ct << 4) + l15][quad << 3];
            short8 bv1 = *(const short8*)&vsh[(ct << 4) + l15][32 + (quad << 3)];
            o_acc[ct] = __builtin_amdgcn_mfma_f32_16x16x32_bf16(a_p0, bv0, o_acc[ct], 0, 0, 0);
            o_acc[ct] = __builtin_amdgcn_mfma_f32_16x16x32_bf16(a_p1, bv1, o_acc[ct], 0, 0, 0);
        }
    }

    // ---- epilogue: normalize, write ob bf16 [b][i][d] ----
#pragma unroll
    for (int ct = 0; ct < 4; ++ct) {
#pragma unroll
        for (int r = 0; r < 4; ++r) {
            const int i = i0 + (w << 4) + (quad << 2) + r;
            const float val = o_acc[ct][r] / l_r[r];
            ob[((size_t)b * T_DIM + i) * D_DIM + h * DH + (ct << 4) + l15] = f2bf(val);
        }
    }
}

// ---------------------------------------------------------------------------
extern "C" void kernel_launch(void* const* d_in, const int* in_sizes, int n_in,
                              void* d_out, int out_size, void* d_ws, size_t ws_size,
                              hipStream_t stream) {
    const float* x = (const float*)d_in[0];
    const float* mem = (const float*)d_in[1];
    const float* wq = (const float*)d_in[2];
    const float* wkv = (const float*)d_in[3];
    const float* wo = (const float*)d_in[4];
    const float* bo = (const float*)d_in[5];
    const float* rel_w = (const float*)d_in[6];

    float* out = (float*)d_out;
    float* mem_next = out + (size_t)B_DIM * T_DIM * D_DIM;

    // workspace layout (shorts), ~80 MB total
    short* kvb = (short*)d_ws;       // 8,388,608  [b][j][d] bf16
    short* qb = kvb + 8388608;       // 4,194,304  [bh][i][c]
    short* kb = qb + 4194304;        // 8,388,608  [bh][j][c]
    short* vTb = kb + 8388608;       // 8,388,608  [bh][c][j]
    short* relb = vTb + 8388608;     // 2,228,224  [h][jp][c]
    short* ob = relb + 2228224;      // 4,194,304  [b*i][d]
    short* wqT = ob + 4194304;       // 1,048,576  [n][k]
    short* wkvT = wqT + 1048576;     // 2,097,152  [n][k]
    short* woT = wkvT + 2097152;     // 1,048,576  [n][k]

    // mem_next = x; kvb = bf16(concat(mem, x))
    hipLaunchKernelGGL(prep_xmem, dim3(8192), dim3(256), 0, stream,
                       x, mem, mem_next, kvb);

    // all weight transposes -> bf16 [n][k]
    hipLaunchKernelGGL(transpose_w3, dim3(32, 64, 3), dim3(32, 8), 0, stream,
                       wq, wkv, wo, wqT, wkvT, woT);

    // rel_w -> relb bf16 [h][jp][c] (padded)
    hipLaunchKernelGGL(convert_rel, dim3(RELPAD / 16, H_DIM), dim3(256), 0, stream,
                       rel_w, relb);

    // q = x @ wq -> qb   (A rows remapped into kvb's x-half)
    hipLaunchKernelGGL((mfma_gemm<1, 0>), dim3(8, 32), dim3(256), 0, stream,
                       kvb, wqT, nullptr, qb, nullptr, nullptr);

    // kv = kvin @ wkv -> kb, vTb
    hipLaunchKernelGGL((mfma_gemm<0, 1>), dim3(16, 64), dim3(256), 0, stream,
                       kvb, wkvT, nullptr, kb, vTb, nullptr);

    // flash attention -> ob bf16
    hipLaunchKernelGGL(flash_attn, dim3(16, 64), dim3(256), 0, stream,
                       qb, kb, vTb, relb, ob);

    // out = ob @ wo + bo -> fp32
    hipLaunchKernelGGL((mfma_gemm<0, 2>), dim3(8, 32), dim3(256), 0, stream,
                       ob, woT, bo, nullptr, nullptr, out);
}

// Round 6
// 432.679 us; speedup vs baseline: 24.8528x; 1.0827x over previous
//
#include <hip/hip_runtime.h>
#include <cstddef>
#include <cstdint>

#define B_DIM 4
#define T_DIM 1024
#define D_DIM 1024
#define H_DIM 16
#define DH 64
#define JDIM 2048
#define MEMLEN 1024
#define RELPAD 2176  // 2048 + 128 zero rows for banded-GEMM overrun

typedef float floatx4 __attribute__((ext_vector_type(4)));
typedef short short8 __attribute__((ext_vector_type(8)));

static __device__ __forceinline__ short f2bf(float f) {
    union { float f; uint32_t u; } v; v.f = f;
    uint32_t r = (v.u + 0x7FFFu + ((v.u >> 16) & 1u)) >> 16;
    return (short)r;
}

// async global->LDS, 16B per lane; LDS dest = wave-uniform base + lane*16
static __device__ __forceinline__ void gl_lds16(const short* g, short* l) {
    __builtin_amdgcn_global_load_lds(
        (const __attribute__((address_space(1))) void*)g,
        (__attribute__((address_space(3))) void*)l, 16, 0, 0);
}

// DPP-based fmax with a cross-lane source (VALU pipe, no LDS)
template <int CTRL>
static __device__ __forceinline__ float dpp_fmax(float v) {
    int y = __builtin_amdgcn_update_dpp(0, __builtin_bit_cast(int, v),
                                        CTRL, 0xF, 0xF, true);
    return fmaxf(v, __builtin_bit_cast(float, y));
}
// 16-lane row reduction: xor1 (quad_perm [1,0,3,2]=0xB1), xor2 ([2,3,0,1]=0x4E),
// row_ror:4 (0x124), row_ror:8 (0x128)
static __device__ __forceinline__ float row16_max(float v) {
    v = dpp_fmax<0xB1>(v);
    v = dpp_fmax<0x4E>(v);
    v = dpp_fmax<0x124>(v);
    v = dpp_fmax<0x128>(v);
    return v;
}

// ---------------------------------------------------------------------------
// Fused: mem_next = x; kvb = bf16(concat(mem, x)).
// ---------------------------------------------------------------------------
__global__ __launch_bounds__(256) void prep_xmem(const float* __restrict__ x,
                                                 const float* __restrict__ mem,
                                                 float* __restrict__ mem_next,
                                                 short* __restrict__ kvb) {
    const size_t gid = (size_t)blockIdx.x * 256 + threadIdx.x;
    if (gid < 1048576) {
        const size_t idx = gid * 4;
        float4 v = *(const float4*)(x + idx);
        *(float4*)(mem_next + idx) = v;
        const int b = (int)(idx >> 20);
        const size_t r = idx & 1048575;
        short4 o;
        o.x = f2bf(v.x); o.y = f2bf(v.y); o.z = f2bf(v.z); o.w = f2bf(v.w);
        *(short4*)(kvb + (size_t)b * 2097152 + 1048576 + r) = o;
    } else {
        const size_t idx = (gid - 1048576) * 4;
        float4 v = *(const float4*)(mem + idx);
        const int b = (int)(idx >> 20);
        const size_t r = idx & 1048575;
        short4 o;
        o.x = f2bf(v.x); o.y = f2bf(v.y); o.z = f2bf(v.z); o.w = f2bf(v.w);
        *(short4*)(kvb + (size_t)b * 2097152 + r) = o;
    }
}

// ---------------------------------------------------------------------------
// All 3 weight transposes in one launch. z=0: wq, z=1: wkv, z=2: wo.
// ---------------------------------------------------------------------------
__global__ __launch_bounds__(256) void transpose_w3(
    const float* __restrict__ wq, const float* __restrict__ wkv,
    const float* __restrict__ wo, short* __restrict__ wqT,
    short* __restrict__ wkvT, short* __restrict__ woT) {
    const int z = blockIdx.z;
    const int N = (z == 1) ? 2048 : 1024;
    if (blockIdx.y * 32 >= N) return;
    const float* w = (z == 0) ? wq : (z == 1) ? wkv : wo;
    short* wT = (z == 0) ? wqT : (z == 1) ? wkvT : woT;
    __shared__ float tile[32][33];
    const int k0 = blockIdx.x * 32, n0 = blockIdx.y * 32;
    const int tx = threadIdx.x, ty = threadIdx.y;
    for (int r = ty; r < 32; r += 8)
        tile[r][tx] = w[(size_t)(k0 + r) * N + n0 + tx];
    __syncthreads();
    for (int r = ty; r < 32; r += 8)
        wT[(size_t)(n0 + r) * 1024 + k0 + tx] = f2bf(tile[tx][r]);
}

// ---------------------------------------------------------------------------
// rel_w fp32 [jp][h][c] -> relb bf16 [h][jp][c], jp in [0,2176), zero pad tail
// ---------------------------------------------------------------------------
__global__ __launch_bounds__(256) void convert_rel(const float* __restrict__ rel,
                                                   short* __restrict__ relb) {
    const int h = blockIdx.y;
    const int jp = blockIdx.x * 16 + (threadIdx.x >> 4);
    const int c = (threadIdx.x & 15) << 2;
    float4 v = make_float4(0.f, 0.f, 0.f, 0.f);
    if (jp < JDIM) v = *(const float4*)(rel + ((size_t)jp * H_DIM + h) * DH + c);
    short4 o;
    o.x = f2bf(v.x); o.y = f2bf(v.y); o.z = f2bf(v.z); o.w = f2bf(v.w);
    *(short4*)(relb + ((size_t)h * RELPAD + jp) * DH + c) = o;
}

// ---------------------------------------------------------------------------
// bf16 MFMA GEMM, 128x128 tile, BK=32, 256 threads (4 waves, 2x2 quadrants),
// global_load_lds width-16 staging, 16x16x32 MFMA, 4x4 tiles per wave.
// ---------------------------------------------------------------------------
template <int AMODE, int CMODE>
__global__ __launch_bounds__(256) void mfma_gemm(
    const short* __restrict__ A, const short* __restrict__ Bt,
    const float* __restrict__ bias,
    short* __restrict__ C0, short* __restrict__ C1, float* __restrict__ Cf) {
    constexpr int K = 1024;
    __shared__ short ash[128 * 32];
    __shared__ short bsh[128 * 32];

    const int tid = threadIdx.x;
    const int w = tid >> 6, lane = tid & 63;
    const int l15 = lane & 15, quad = lane >> 4;
    const int wr = w >> 1, wc = w & 1;
    const int row0 = blockIdx.y << 7, col0 = blockIdx.x << 7;

    const int sk = (lane & 3) << 3;
    int tr0 = row0 + (w << 5) + (lane >> 2);
    int tr1 = tr0 + 16;
    if (AMODE == 1) {
        tr0 = ((tr0 >> 10) << 11) + 1024 + (tr0 & 1023);
        tr1 = ((tr1 >> 10) << 11) + 1024 + (tr1 & 1023);
    }
    const short* ap0 = A + (size_t)tr0 * K + sk;
    const short* ap1 = A + (size_t)tr1 * K + sk;
    const short* bp0 = Bt + (size_t)(col0 + (w << 5) + (lane >> 2)) * K + sk;
    const short* bp1 = bp0 + (size_t)16 * K;

    floatx4 acc[4][4] = {};

    for (int k0 = 0; k0 < K; k0 += 32) {
        __syncthreads();
        gl_lds16(ap0 + k0, ash + (w << 10));
        gl_lds16(ap1 + k0, ash + (w << 10) + 512);
        gl_lds16(bp0 + k0, bsh + (w << 10));
        gl_lds16(bp1 + k0, bsh + (w << 10) + 512);
        __syncthreads();

        short8 af[4];
#pragma unroll
        for (int mt = 0; mt < 4; ++mt)
            af[mt] = *(const short8*)&ash[(((wr << 6) + (mt << 4) + l15) << 5) + (quad << 3)];
#pragma unroll
        for (int nt = 0; nt < 4; ++nt) {
            short8 bf = *(const short8*)&bsh[(((wc << 6) + (nt << 4) + l15) << 5) + (quad << 3)];
#pragma unroll
            for (int mt = 0; mt < 4; ++mt)
                acc[mt][nt] = __builtin_amdgcn_mfma_f32_16x16x32_bf16(af[mt], bf, acc[mt][nt], 0, 0, 0);
        }
    }

#pragma unroll
    for (int nt = 0; nt < 4; ++nt) {
        const int col = col0 + (wc << 6) + (nt << 4) + l15;
        float bv = (CMODE == 2) ? bias[col] : 0.f;
#pragma unroll
        for (int mt = 0; mt < 4; ++mt) {
#pragma unroll
            for (int rr = 0; rr < 4; ++rr) {
                const int row = row0 + (wr << 6) + (mt << 4) + (quad << 2) + rr;
                const float val = acc[mt][nt][rr];
                if (CMODE == 0) {
                    int b = row >> 10, i = row & 1023, h = col >> 6, c = col & 63;
                    C0[(((size_t)b * H_DIM + h) * T_DIM + i) * DH + c] = f2bf(val);
                } else if (CMODE == 1) {
                    int b = row >> 11, j = row & 2047;
                    if (col < 1024) {
                        int h = col >> 6, c = col & 63;
                        C0[(((size_t)b * H_DIM + h) * JDIM + j) * DH + c] = f2bf(val);
                    } else {
                        int n2 = col - 1024, h = n2 >> 6, c = n2 & 63;
                        C1[(((size_t)b * H_DIM + h) * DH + c) * JDIM + j] = f2bf(val);
                    }
                } else {
                    Cf[(size_t)row * 1024 + col] = val + bv;
                }
            }
        }
    }
}

// ---------------------------------------------------------------------------
// Flash attention v3. Block = (bh, 64-query i-tile), 4 waves, wave w owns
// rows [16w,16w+16). LDS tiles stored in FRAGMENT ORDER [chunk][lane][16B] and
// staged by global_load_lds (no ds_write, conflict-free ds_read_b128):
//   kshf: chunk = nt*2+half  -> K[j0+nt*16+l15][half*32+quad*8 ..]
//   vshf: chunk = ct*2+half  -> vT[ct*16+l15][j0+half*32+quad*8 ..]
//   rshf: chunk = rb*2+half  -> rel[base0+rb*16+l15][half*32+quad*8 ..]
// Rel band per wave: G blocks gi+goff (goff=3-w), gi in [0,5); shifted-rel
// gather via ONE bpermute of packed bf16 pair (G[nt],G[nt+1]). Row max via
// DPP (VALU). P round-trips through wave-private psh. l via ones-MFMA.
// LDS 41.4 KB -> 3 blocks/CU.
// ---------------------------------------------------------------------------
__global__ __launch_bounds__(256, 3) void flash_attn(
    const short* __restrict__ qb, const short* __restrict__ kb,
    const short* __restrict__ vTb, const short* __restrict__ relb,
    short* __restrict__ ob) {
    __shared__ short kshf[8 * 512];   // 8 chunks x 1KB
    __shared__ short vshf[8 * 512];
    __shared__ short rshf[16 * 512];
    __shared__ short psh[64][72];     // P tile, wave-private rows

    const int tid = threadIdx.x;
    const int w = tid >> 6;
    const int lane = tid & 63;
    const int l15 = lane & 15, quad = lane >> 4;
    const int bh = blockIdx.y, h = bh & 15, b = bh >> 4;
    const int i0 = blockIdx.x << 6;
    const int goff = 3 - w;

    const short* kb_b = kb + (size_t)bh * JDIM * DH;
    const short* vT_b = vTb + (size_t)bh * DH * JDIM;
    const short* rel_b = relb + (size_t)h * RELPAD * DH;

    // Q fragments straight from global (row is 128B-aligned)
    const short* qrow = qb + ((size_t)bh * T_DIM + i0 + (w << 4) + l15) * DH;
    const short8 a_q0 = *(const short8*)(qrow + (quad << 3));
    const short8 a_q1 = *(const short8*)(qrow + 32 + (quad << 3));

    // staging source pointers (advance per jt). chunk ch: blk = ch>>1, half = ch&1
    // lane part: row += l15, col = half*32 + quad*8
    const int kc0 = w, kc1 = w + 4;  // K and V chunks for this wave
    const short* kp0 = kb_b + (size_t)((kc0 >> 1) * 16 + l15) * DH + (kc0 & 1) * 32 + (quad << 3);
    const short* kp1 = kb_b + (size_t)((kc1 >> 1) * 16 + l15) * DH + (kc1 & 1) * 32 + (quad << 3);
    const short* vp0 = vT_b + (size_t)((kc0 >> 1) * 16 + l15) * JDIM + (kc0 & 1) * 32 + (quad << 3);
    const short* vp1 = vT_b + (size_t)((kc1 >> 1) * 16 + l15) * JDIM + (kc1 & 1) * 32 + (quad << 3);
    const int base00 = 960 - i0;  // base0 at jt=0 (>= 0)
    const short* rp[4];
#pragma unroll
    for (int s = 0; s < 4; ++s) {
        const int ch = w + (s << 2);
        rp[s] = rel_b + (size_t)(base00 + (ch >> 1) * 16 + l15) * DH + (ch & 1) * 32 + (quad << 3);
    }

    // all-ones B fragment for row-sum MFMA
    short8 ones8;
#pragma unroll
    for (int z = 0; z < 8; ++z) ones8[z] = (short)0x3F80;

    // gather controls: per target reg r, source lane & hi/lo select
    int srcl[4], gsel[4];
#pragma unroll
    for (int r = 0; r < 4; ++r) {
        const int t = l15 - (quad << 2) - r + 15;  // in [0,30]
        gsel[r] = t >> 4;
        srcl[r] = (quad << 4) | (t & 15);
    }

    floatx4 o_acc[4] = {};
    float m_r[4], l_r[4];
#pragma unroll
    for (int r = 0; r < 4; ++r) { m_r[r] = -3.0e38f; l_r[r] = 0.f; }

    const int jt_end = (i0 >> 6) + 17;
    const float SC = 0.18033688f;  // 0.125 * log2(e)

    for (int jt = 0; jt < jt_end; ++jt) {
        __syncthreads();  // all waves done reading prev tiles
        // stage K (2), V (2), rel (4) chunks for this wave
        gl_lds16(kp0, kshf + (size_t)kc0 * 512);
        gl_lds16(kp1, kshf + (size_t)kc1 * 512);
        gl_lds16(vp0, vshf + (size_t)kc0 * 512);
        gl_lds16(vp1, vshf + (size_t)kc1 * 512);
#pragma unroll
        for (int s = 0; s < 4; ++s)
            gl_lds16(rp[s], rshf + (size_t)(w + (s << 2)) * 512);
        kp0 += 64 * DH; kp1 += 64 * DH;       // next j-tile rows
        vp0 += 64; vp1 += 64;                 // next j columns
#pragma unroll
        for (int s = 0; s < 4; ++s) rp[s] += 64 * DH;
        __syncthreads();  // vmcnt drained at barrier -> stage visible

        // ---- QK^T ----
        floatx4 s_acc[4];
#pragma unroll
        for (int nt = 0; nt < 4; ++nt) {
            short8 bk0 = *(const short8*)&kshf[(((nt << 1) + 0) << 9) + (lane << 3)];
            short8 bk1 = *(const short8*)&kshf[(((nt << 1) + 1) << 9) + (lane << 3)];
            floatx4 acc = {0.f, 0.f, 0.f, 0.f};
            acc = __builtin_amdgcn_mfma_f32_16x16x32_bf16(a_q0, bk0, acc, 0, 0, 0);
            acc = __builtin_amdgcn_mfma_f32_16x16x32_bf16(a_q1, bk1, acc, 0, 0, 0);
            s_acc[nt] = acc;
        }

        // ---- banded rel: G blocks gi+goff, gi in [0,5) ----
        floatx4 G[5];
#pragma unroll
        for (int gi = 0; gi < 5; ++gi) {
            const int rb = gi + goff;
            short8 br0 = *(const short8*)&rshf[(((rb << 1) + 0) << 9) + (lane << 3)];
            short8 br1 = *(const short8*)&rshf[(((rb << 1) + 1) << 9) + (lane << 3)];
            floatx4 acc = {0.f, 0.f, 0.f, 0.f};
            acc = __builtin_amdgcn_mfma_f32_16x16x32_bf16(a_q0, br0, acc, 0, 0, 0);
            G[gi] = __builtin_amdgcn_mfma_f32_16x16x32_bf16(a_q1, br1, acc, 0, 0, 0);
        }

        // ---- pack (G[gi],G[gi+1]) hi-halves -> one bpermute per gather ----
        uint32_t pk[4][4];
#pragma unroll
        for (int gi = 0; gi < 4; ++gi)
#pragma unroll
            for (int r = 0; r < 4; ++r) {
                uint32_t g0 = __builtin_bit_cast(uint32_t, G[gi][r]);
                uint32_t g1 = __builtin_bit_cast(uint32_t, G[gi + 1][r]);
                pk[gi][r] = (g0 & 0xFFFF0000u) | (g1 >> 16);
            }
#pragma unroll
        for (int nt = 0; nt < 4; ++nt)
#pragma unroll
            for (int r = 0; r < 4; ++r) {
                uint32_t pv = (uint32_t)__shfl((int)pk[nt][r], srcl[r], 64);
                uint32_t gb = gsel[r] ? (pv << 16) : (pv & 0xFFFF0000u);
                s_acc[nt][r] = (s_acc[nt][r] + __builtin_bit_cast(float, gb)) * SC;
            }
        if (jt == jt_end - 1) {  // triangular mask: valid iff u <= v
#pragma unroll
            for (int nt = 0; nt < 4; ++nt) {
                const int u = (nt << 4) + l15;
#pragma unroll
                for (int r = 0; r < 4; ++r) {
                    const int v = (w << 4) + (quad << 2) + r;
                    if (u > v) s_acc[nt][r] = -3.0e38f;
                }
            }
        }

        // ---- online softmax (row max via DPP, VALU pipe) ----
#pragma unroll
        for (int r = 0; r < 4; ++r) {
            float tm = fmaxf(fmaxf(s_acc[0][r], s_acc[1][r]),
                             fmaxf(s_acc[2][r], s_acc[3][r]));
            tm = row16_max(tm);
            const float mx = fmaxf(m_r[r], tm);
            const float alpha = exp2f(m_r[r] - mx);
            m_r[r] = mx;
            l_r[r] *= alpha;
#pragma unroll
            for (int ct = 0; ct < 4; ++ct) o_acc[ct][r] *= alpha;
#pragma unroll
            for (int nt = 0; nt < 4; ++nt) {
                const float p = exp2f(s_acc[nt][r] - mx);
                psh[(w << 4) + (quad << 2) + r][(nt << 4) + l15] = f2bf(p);
            }
        }
        // no barrier: psh rows are wave-private

        // ---- PV + row-sum ----
        const short8 a_p0 = *(const short8*)&psh[(w << 4) + l15][quad << 3];
        const short8 a_p1 = *(const short8*)&psh[(w << 4) + l15][32 + (quad << 3)];
        floatx4 ls = {0.f, 0.f, 0.f, 0.f};
        ls = __builtin_amdgcn_mfma_f32_16x16x32_bf16(a_p0, ones8, ls, 0, 0, 0);
        ls = __builtin_amdgcn_mfma_f32_16x16x32_bf16(a_p1, ones8, ls, 0, 0, 0);
#pragma unroll
        for (int r = 0; r < 4; ++r) l_r[r] += ls[r];
#pragma unroll
        for (int ct = 0; ct < 4; ++ct) {
            short8 bv0 = *(const short8*)&vshf[(((ct << 1) + 0) << 9) + (lane << 3)];
            short8 bv1 = *(const short8*)&vshf[(((ct << 1) + 1) << 9) + (lane << 3)];
            o_acc[ct] = __builtin_amdgcn_mfma_f32_16x16x32_bf16(a_p0, bv0, o_acc[ct], 0, 0, 0);
            o_acc[ct] = __builtin_amdgcn_mfma_f32_16x16x32_bf16(a_p1, bv1, o_acc[ct], 0, 0, 0);
        }
    }

    // ---- epilogue: normalize, write ob bf16 [b][i][d] ----
#pragma unroll
    for (int ct = 0; ct < 4; ++ct) {
#pragma unroll
        for (int r = 0; r < 4; ++r) {
            const int i = i0 + (w << 4) + (quad << 2) + r;
            const float val = o_acc[ct][r] / l_r[r];
            ob[((size_t)b * T_DIM + i) * D_DIM + h * DH + (ct << 4) + l15] = f2bf(val);
        }
    }
}

// ---------------------------------------------------------------------------
extern "C" void kernel_launch(void* const* d_in, const int* in_sizes, int n_in,
                              void* d_out, int out_size, void* d_ws, size_t ws_size,
                              hipStream_t stream) {
    const float* x = (const float*)d_in[0];
    const float* mem = (const float*)d_in[1];
    const float* wq = (const float*)d_in[2];
    const float* wkv = (const float*)d_in[3];
    const float* wo = (const float*)d_in[4];
    const float* bo = (const float*)d_in[5];
    const float* rel_w = (const float*)d_in[6];

    float* out = (float*)d_out;
    float* mem_next = out + (size_t)B_DIM * T_DIM * D_DIM;

    // workspace layout (shorts), ~80 MB total
    short* kvb = (short*)d_ws;       // 8,388,608  [b][j][d] bf16
    short* qb = kvb + 8388608;       // 4,194,304  [bh][i][c]
    short* kb = qb + 4194304;        // 8,388,608  [bh][j][c]
    short* vTb = kb + 8388608;       // 8,388,608  [bh][c][j]
    short* relb = vTb + 8388608;     // 2,228,224  [h][jp][c]
    short* ob = relb + 2228224;      // 4,194,304  [b*i][d]
    short* wqT = ob + 4194304;       // 1,048,576  [n][k]
    short* wkvT = wqT + 1048576;     // 2,097,152  [n][k]
    short* woT = wkvT + 2097152;     // 1,048,576  [n][k]

    // mem_next = x; kvb = bf16(concat(mem, x))
    hipLaunchKernelGGL(prep_xmem, dim3(8192), dim3(256), 0, stream,
                       x, mem, mem_next, kvb);

    // all weight transposes -> bf16 [n][k]
    hipLaunchKernelGGL(transpose_w3, dim3(32, 64, 3), dim3(32, 8), 0, stream,
                       wq, wkv, wo, wqT, wkvT, woT);

    // rel_w -> relb bf16 [h][jp][c] (padded)
    hipLaunchKernelGGL(convert_rel, dim3(RELPAD / 16, H_DIM), dim3(256), 0, stream,
                       rel_w, relb);

    // q = x @ wq -> qb   (A rows remapped into kvb's x-half)
    hipLaunchKernelGGL((mfma_gemm<1, 0>), dim3(8, 32), dim3(256), 0, stream,
                       kvb, wqT, nullptr, qb, nullptr, nullptr);

    // kv = kvin @ wkv -> kb, vTb
    hipLaunchKernelGGL((mfma_gemm<0, 1>), dim3(16, 64), dim3(256), 0, stream,
                       kvb, wkvT, nullptr, kb, vTb, nullptr);

    // flash attention -> ob bf16
    hipLaunchKernelGGL(flash_attn, dim3(16, 64), dim3(256), 0, stream,
                       qb, kb, vTb, relb, ob);

    // out = ob @ wo + bo -> fp32
    hipLaunchKernelGGL((mfma_gemm<0, 2>), dim3(8, 32), dim3(256), 0, stream,
                       ob, woT, bo, nullptr, nullptr, out);
}

// Round 7
// 354.265 us; speedup vs baseline: 30.3538x; 1.2213x over previous
//
#include <hip/hip_runtime.h>
#include <cstddef>
#include <cstdint>

#define B_DIM 4
#define T_DIM 1024
#define D_DIM 1024
#define H_DIM 16
#define DH 64
#define JDIM 2048
#define MEMLEN 1024
#define RELPAD 2176  // 2048 + 128 zero rows for banded-GEMM overrun

typedef float floatx4 __attribute__((ext_vector_type(4)));
typedef short short8 __attribute__((ext_vector_type(8)));

static __device__ __forceinline__ short f2bf(float f) {
    union { float f; uint32_t u; } v; v.f = f;
    uint32_t r = (v.u + 0x7FFFu + ((v.u >> 16) & 1u)) >> 16;
    return (short)r;
}

// async global->LDS, 16B per lane; LDS dest = wave-uniform base + lane*16
static __device__ __forceinline__ void gl_lds16(const short* g, short* l) {
    __builtin_amdgcn_global_load_lds(
        (const __attribute__((address_space(1))) void*)g,
        (__attribute__((address_space(3))) void*)l, 16, 0, 0);
}

// DPP-based fmax with a cross-lane source (VALU pipe, no LDS)
template <int CTRL>
static __device__ __forceinline__ float dpp_fmax(float v) {
    int y = __builtin_amdgcn_update_dpp(0, __builtin_bit_cast(int, v),
                                        CTRL, 0xF, 0xF, true);
    return fmaxf(v, __builtin_bit_cast(float, y));
}
static __device__ __forceinline__ float row16_max(float v) {
    v = dpp_fmax<0xB1>(v);    // quad_perm xor1
    v = dpp_fmax<0x4E>(v);    // quad_perm xor2
    v = dpp_fmax<0x124>(v);   // row_ror:4
    v = dpp_fmax<0x128>(v);   // row_ror:8
    return v;
}

// ---------------------------------------------------------------------------
// Fused: mem_next = x; kvb = bf16(concat(mem, x)).
// ---------------------------------------------------------------------------
__global__ __launch_bounds__(256) void prep_xmem(const float* __restrict__ x,
                                                 const float* __restrict__ mem,
                                                 float* __restrict__ mem_next,
                                                 short* __restrict__ kvb) {
    const size_t gid = (size_t)blockIdx.x * 256 + threadIdx.x;
    if (gid < 1048576) {
        const size_t idx = gid * 4;
        float4 v = *(const float4*)(x + idx);
        *(float4*)(mem_next + idx) = v;
        const int b = (int)(idx >> 20);
        const size_t r = idx & 1048575;
        short4 o;
        o.x = f2bf(v.x); o.y = f2bf(v.y); o.z = f2bf(v.z); o.w = f2bf(v.w);
        *(short4*)(kvb + (size_t)b * 2097152 + 1048576 + r) = o;
    } else {
        const size_t idx = (gid - 1048576) * 4;
        float4 v = *(const float4*)(mem + idx);
        const int b = (int)(idx >> 20);
        const size_t r = idx & 1048575;
        short4 o;
        o.x = f2bf(v.x); o.y = f2bf(v.y); o.z = f2bf(v.z); o.w = f2bf(v.w);
        *(short4*)(kvb + (size_t)b * 2097152 + r) = o;
    }
}

// ---------------------------------------------------------------------------
// Weight transposes. z=0: wq -> wkvqT rows [2048,3072); z=1: wkv -> wkvqT
// rows [0,2048); z=2: wo -> woT. wT[n][k] bf16 = w[k][n] fp32.
// ---------------------------------------------------------------------------
__global__ __launch_bounds__(256) void transpose_w3(
    const float* __restrict__ wq, const float* __restrict__ wkv,
    const float* __restrict__ wo, short* __restrict__ wkvqT,
    short* __restrict__ woT) {
    const int z = blockIdx.z;
    const int N = (z == 1) ? 2048 : 1024;
    if (blockIdx.y * 32 >= N) return;
    const float* w = (z == 0) ? wq : (z == 1) ? wkv : wo;
    short* wT = (z == 0) ? (wkvqT + (size_t)2048 * 1024) : (z == 1) ? wkvqT : woT;
    __shared__ float tile[32][33];
    const int k0 = blockIdx.x * 32, n0 = blockIdx.y * 32;
    const int tx = threadIdx.x, ty = threadIdx.y;
    for (int r = ty; r < 32; r += 8)
        tile[r][tx] = w[(size_t)(k0 + r) * N + n0 + tx];
    __syncthreads();
    for (int r = ty; r < 32; r += 8)
        wT[(size_t)(n0 + r) * 1024 + k0 + tx] = f2bf(tile[tx][r]);
}

// ---------------------------------------------------------------------------
// rel_w fp32 [jp][h][c] -> relb bf16 [h][jp][c], jp in [0,2176), zero pad tail
// ---------------------------------------------------------------------------
__global__ __launch_bounds__(256) void convert_rel(const float* __restrict__ rel,
                                                   short* __restrict__ relb) {
    const int h = blockIdx.y;
    const int jp = blockIdx.x * 16 + (threadIdx.x >> 4);
    const int c = (threadIdx.x & 15) << 2;
    float4 v = make_float4(0.f, 0.f, 0.f, 0.f);
    if (jp < JDIM) v = *(const float4*)(rel + ((size_t)jp * H_DIM + h) * DH + c);
    short4 o;
    o.x = f2bf(v.x); o.y = f2bf(v.y); o.z = f2bf(v.z); o.w = f2bf(v.w);
    *(short4*)(relb + ((size_t)h * RELPAD + jp) * DH + c) = o;
}

// ---------------------------------------------------------------------------
// bf16 MFMA GEMM, 128x128 tile, BK=32, 256 threads (4 waves, 2x2 quadrants).
// CMODE 1 (fused kvq): Bt = wkvqT [3072][1024], grid (24, 64).
//   col<1024 -> kb [bh][j][c]; col<2048 -> vTb [bh][c][j];
//   col>=2048 -> qb [bh][i][c], x-half rows only (mem-row tiles early-exit).
// CMODE 2: out = A @ Bt^T + bias -> Cf fp32 [r][n].
// ---------------------------------------------------------------------------
template <int CMODE>
__global__ __launch_bounds__(256) void mfma_gemm(
    const short* __restrict__ A, const short* __restrict__ Bt,
    const float* __restrict__ bias,
    short* __restrict__ C0, short* __restrict__ C1, short* __restrict__ C2,
    float* __restrict__ Cf) {
    constexpr int K = 1024;
    const int row0 = blockIdx.y << 7, col0 = blockIdx.x << 7;
    if (CMODE == 1 && col0 >= 2048 && (row0 & 2047) < 1024) return;  // q x mem-rows

    __shared__ short ash[128 * 32];
    __shared__ short bsh[128 * 32];

    const int tid = threadIdx.x;
    const int w = tid >> 6, lane = tid & 63;
    const int l15 = lane & 15, quad = lane >> 4;
    const int wr = w >> 1, wc = w & 1;

    const int sk = (lane & 3) << 3;
    const short* ap0 = A + (size_t)(row0 + (w << 5) + (lane >> 2)) * K + sk;
    const short* ap1 = ap0 + (size_t)16 * K;
    const short* bp0 = Bt + (size_t)(col0 + (w << 5) + (lane >> 2)) * K + sk;
    const short* bp1 = bp0 + (size_t)16 * K;

    floatx4 acc[4][4] = {};

    for (int k0 = 0; k0 < K; k0 += 32) {
        __syncthreads();
        gl_lds16(ap0 + k0, ash + (w << 10));
        gl_lds16(ap1 + k0, ash + (w << 10) + 512);
        gl_lds16(bp0 + k0, bsh + (w << 10));
        gl_lds16(bp1 + k0, bsh + (w << 10) + 512);
        __syncthreads();

        short8 af[4];
#pragma unroll
        for (int mt = 0; mt < 4; ++mt)
            af[mt] = *(const short8*)&ash[(((wr << 6) + (mt << 4) + l15) << 5) + (quad << 3)];
#pragma unroll
        for (int nt = 0; nt < 4; ++nt) {
            short8 bf = *(const short8*)&bsh[(((wc << 6) + (nt << 4) + l15) << 5) + (quad << 3)];
#pragma unroll
            for (int mt = 0; mt < 4; ++mt)
                acc[mt][nt] = __builtin_amdgcn_mfma_f32_16x16x32_bf16(af[mt], bf, acc[mt][nt], 0, 0, 0);
        }
    }

#pragma unroll
    for (int nt = 0; nt < 4; ++nt) {
        const int col = col0 + (wc << 6) + (nt << 4) + l15;
        float bv = (CMODE == 2) ? bias[col] : 0.f;
#pragma unroll
        for (int mt = 0; mt < 4; ++mt) {
#pragma unroll
            for (int rr = 0; rr < 4; ++rr) {
                const int row = row0 + (wr << 6) + (mt << 4) + (quad << 2) + rr;
                const float val = acc[mt][nt][rr];
                if (CMODE == 1) {
                    int b = row >> 11, j = row & 2047;
                    if (col < 1024) {
                        int h = col >> 6, c = col & 63;
                        C0[(((size_t)b * H_DIM + h) * JDIM + j) * DH + c] = f2bf(val);
                    } else if (col < 2048) {
                        int n2 = col - 1024, h = n2 >> 6, c = n2 & 63;
                        C1[(((size_t)b * H_DIM + h) * DH + c) * JDIM + j] = f2bf(val);
                    } else {
                        int n2 = col - 2048, h = n2 >> 6, c = n2 & 63;
                        int i = j - 1024;  // guaranteed >= 0 by early-exit
                        C2[(((size_t)b * H_DIM + h) * T_DIM + i) * DH + c] = f2bf(val);
                    }
                } else {
                    Cf[(size_t)row * 1024 + col] = val + bv;
                }
            }
        }
    }
}

// ---------------------------------------------------------------------------
// Flash attention v4: software-pipelined. Block = (bh, 64-query i-tile),
// 4 waves. Single-buffer K/V + mod-3 rolling rel ring (64-row segments; tiles
// jt and jt+1 share 64 rel rows -> stage only 64 new rows/iter).
// Pipeline (2 barriers/iter, prefetch issued right AFTER each barrier so the
// auto-drain at the NEXT barrier lands a full compute phase later):
//   QK+relG+gather | b1 (drains V(jt)) | issue K(jt+1)+rel seg |
//   softmax+psh+PV | b2 (drains K/rel) | issue V(jt+1)
// LDS 49 KB -> 3 blocks/CU. Heavy-first i-tile swizzle for tail balance.
// ---------------------------------------------------------------------------
__global__ __launch_bounds__(256, 3) void flash_attn(
    const short* __restrict__ qb, const short* __restrict__ kb,
    const short* __restrict__ vTb, const short* __restrict__ relb,
    short* __restrict__ ob) {
    __shared__ short kshf[8 * 512];       // 8 KB
    __shared__ short vshf[8 * 512];       // 8 KB
    __shared__ short rshf[3 * 8 * 512];   // 24 KB, 3-seg ring (64 rows/seg)
    __shared__ short psh[64][72];         // 9 KB, wave-private rows

    const int tid = threadIdx.x;
    const int w = tid >> 6;
    const int lane = tid & 63;
    const int l15 = lane & 15, quad = lane >> 4;
    const int bh = blockIdx.y, h = bh & 15, b = bh >> 4;
    const int i0 = (15 - blockIdx.x) << 6;  // heavy-first swizzle
    const int goff = 3 - w;

    const short* kb_b = kb + (size_t)bh * JDIM * DH;
    const short* vT_b = vTb + (size_t)bh * DH * JDIM;
    const short* rel_b = relb + (size_t)h * RELPAD * DH;

    // Q fragments straight from global
    const short* qrow = qb + ((size_t)bh * T_DIM + i0 + (w << 4) + l15) * DH;
    const short8 a_q0 = *(const short8*)(qrow + (quad << 3));
    const short8 a_q1 = *(const short8*)(qrow + 32 + (quad << 3));

    // staging pointers: wave w owns chunks {w, w+4} of each tile
    const int kc0 = w, kc1 = w + 4;
    const short* kp0 = kb_b + (size_t)(((kc0 >> 1) << 4) + l15) * DH + (kc0 & 1) * 32 + (quad << 3);
    const short* kp1 = kb_b + (size_t)(((kc1 >> 1) << 4) + l15) * DH + (kc1 & 1) * 32 + (quad << 3);
    const short* vp0 = vT_b + (size_t)(((kc0 >> 1) << 4) + l15) * JDIM + (kc0 & 1) * 32 + (quad << 3);
    const short* vp1 = vT_b + (size_t)(((kc1 >> 1) << 4) + l15) * JDIM + (kc1 & 1) * 32 + (quad << 3);
    const int base00 = 960 - i0;  // >= 0

    // ---- prologue: K(0), V(0), rel segs 0,1 (128 rows) ----
    gl_lds16(kp0, kshf + (kc0 << 9));
    gl_lds16(kp1, kshf + (kc1 << 9));
    gl_lds16(vp0, vshf + (kc0 << 9));
    gl_lds16(vp1, vshf + (kc1 << 9));
    kp0 += 64 * DH; kp1 += 64 * DH; vp0 += 64; vp1 += 64;
#pragma unroll
    for (int s = 0; s < 4; ++s) {
        const int c4 = w + (s << 2);  // chunk over segs 0..1 (contiguous)
        const short* rp = rel_b + (size_t)(base00 + ((c4 >> 1) << 4) + l15) * DH +
                          (c4 & 1) * 32 + (quad << 3);
        gl_lds16(rp, rshf + (c4 << 9));
    }
    // steady-state rel write pointers (rows base0+128.., chunks w, w+4 of seg s2)
    const short* rw0 = rel_b + (size_t)(base00 + 128 + ((w >> 1) << 4) + l15) * DH +
                       (w & 1) * 32 + (quad << 3);
    const short* rw1 = rel_b + (size_t)(base00 + 128 + (((w + 4) >> 1) << 4) + l15) * DH +
                       ((w + 4) & 1) * 32 + (quad << 3);
    __syncthreads();  // drain prologue

    // all-ones B fragment for row-sum MFMA
    short8 ones8;
#pragma unroll
    for (int z = 0; z < 8; ++z) ones8[z] = (short)0x3F80;

    // gather controls
    int srcl[4], gsel[4];
#pragma unroll
    for (int r = 0; r < 4; ++r) {
        const int t = l15 - (quad << 2) - r + 15;
        gsel[r] = t >> 4;
        srcl[r] = (quad << 4) | (t & 15);
    }

    floatx4 o_acc[4] = {};
    float m_r[4], l_r[4];
#pragma unroll
    for (int r = 0; r < 4; ++r) { m_r[r] = -3.0e38f; l_r[r] = 0.f; }

    const int jt_end = (i0 >> 6) + 17;
    const float SC = 0.18033688f;  // 0.125 * log2(e)
    int s0 = 0, s1 = 1, s2 = 2;    // ring segs: jt, jt+1, prefetch target

    for (int jt = 0; jt < jt_end; ++jt) {
        // ---- QK^T ----
        floatx4 s_acc[4];
#pragma unroll
        for (int nt = 0; nt < 4; ++nt) {
            short8 bk0 = *(const short8*)&kshf[((nt << 1) << 9) + (lane << 3)];
            short8 bk1 = *(const short8*)&kshf[(((nt << 1) + 1) << 9) + (lane << 3)];
            floatx4 acc = {0.f, 0.f, 0.f, 0.f};
            acc = __builtin_amdgcn_mfma_f32_16x16x32_bf16(a_q0, bk0, acc, 0, 0, 0);
            acc = __builtin_amdgcn_mfma_f32_16x16x32_bf16(a_q1, bk1, acc, 0, 0, 0);
            s_acc[nt] = acc;
        }

        // ---- banded rel: G blocks rb = gi+goff, gi in [0,5); ring seg by rb>=4
        floatx4 G[5];
#pragma unroll
        for (int gi = 0; gi < 5; ++gi) {
            const int rb = gi + goff;
            const int seg = (rb & 4) ? s1 : s0;
            const int ch = (seg << 3) + ((rb & 3) << 1);
            short8 br0 = *(const short8*)&rshf[(ch << 9) + (lane << 3)];
            short8 br1 = *(const short8*)&rshf[((ch + 1) << 9) + (lane << 3)];
            floatx4 acc = {0.f, 0.f, 0.f, 0.f};
            acc = __builtin_amdgcn_mfma_f32_16x16x32_bf16(a_q0, br0, acc, 0, 0, 0);
            G[gi] = __builtin_amdgcn_mfma_f32_16x16x32_bf16(a_q1, br1, acc, 0, 0, 0);
        }

        // ---- pack + gather shifted rel ----
        uint32_t pk[4][4];
#pragma unroll
        for (int gi = 0; gi < 4; ++gi)
#pragma unroll
            for (int r = 0; r < 4; ++r) {
                uint32_t g0 = __builtin_bit_cast(uint32_t, G[gi][r]);
                uint32_t g1 = __builtin_bit_cast(uint32_t, G[gi + 1][r]);
                pk[gi][r] = (g0 & 0xFFFF0000u) | (g1 >> 16);
            }
#pragma unroll
        for (int nt = 0; nt < 4; ++nt)
#pragma unroll
            for (int r = 0; r < 4; ++r) {
                uint32_t pv = (uint32_t)__shfl((int)pk[nt][r], srcl[r], 64);
                uint32_t gb = gsel[r] ? (pv << 16) : (pv & 0xFFFF0000u);
                s_acc[nt][r] = (s_acc[nt][r] + __builtin_bit_cast(float, gb)) * SC;
            }
        if (jt == jt_end - 1) {  // triangular mask: valid iff u <= v
#pragma unroll
            for (int nt = 0; nt < 4; ++nt) {
                const int u = (nt << 4) + l15;
#pragma unroll
                for (int r = 0; r < 4; ++r) {
                    const int v = (w << 4) + (quad << 2) + r;
                    if (u > v) s_acc[nt][r] = -3.0e38f;
                }
            }
        }

        __syncthreads();  // b1: drains V(jt); all waves done K/rel reads
        if (jt + 1 < jt_end) {  // prefetch K(jt+1), rel seg s2 (drained at b2)
            gl_lds16(kp0, kshf + (kc0 << 9));
            gl_lds16(kp1, kshf + (kc1 << 9));
            gl_lds16(rw0, rshf + (s2 << 12) + (w << 9));
            gl_lds16(rw1, rshf + (s2 << 12) + ((w + 4) << 9));
            kp0 += 64 * DH; kp1 += 64 * DH; rw0 += 64 * DH; rw1 += 64 * DH;
        }

        // ---- online softmax (DPP row max) ----
#pragma unroll
        for (int r = 0; r < 4; ++r) {
            float tm = fmaxf(fmaxf(s_acc[0][r], s_acc[1][r]),
                             fmaxf(s_acc[2][r], s_acc[3][r]));
            tm = row16_max(tm);
            const float mx = fmaxf(m_r[r], tm);
            const float alpha = exp2f(m_r[r] - mx);
            m_r[r] = mx;
            l_r[r] *= alpha;
#pragma unroll
            for (int ct = 0; ct < 4; ++ct) o_acc[ct][r] *= alpha;
#pragma unroll
            for (int nt = 0; nt < 4; ++nt) {
                const float p = exp2f(s_acc[nt][r] - mx);
                psh[(w << 4) + (quad << 2) + r][(nt << 4) + l15] = f2bf(p);
            }
        }

        // ---- PV + row-sum (reads V(jt), drained at b1) ----
        const short8 a_p0 = *(const short8*)&psh[(w << 4) + l15][quad << 3];
        const short8 a_p1 = *(const short8*)&psh[(w << 4) + l15][32 + (quad << 3)];
        floatx4 ls = {0.f, 0.f, 0.f, 0.f};
        ls = __builtin_amdgcn_mfma_f32_16x16x32_bf16(a_p0, ones8, ls, 0, 0, 0);
        ls = __builtin_amdgcn_mfma_f32_16x16x32_bf16(a_p1, ones8, ls, 0, 0, 0);
#pragma unroll
        for (int r = 0; r < 4; ++r) l_r[r] += ls[r];
#pragma unroll
        for (int ct = 0; ct < 4; ++ct) {
            short8 bv0 = *(const short8*)&vshf[((ct << 1) << 9) + (lane << 3)];
            short8 bv1 = *(const short8*)&vshf[(((ct << 1) + 1) << 9) + (lane << 3)];
            o_acc[ct] = __builtin_amdgcn_mfma_f32_16x16x32_bf16(a_p0, bv0, o_acc[ct], 0, 0, 0);
            o_acc[ct] = __builtin_amdgcn_mfma_f32_16x16x32_bf16(a_p1, bv1, o_acc[ct], 0, 0, 0);
        }

        __syncthreads();  // b2: drains K(jt+1)/rel; V buffer free
        if (jt + 1 < jt_end) {  // prefetch V(jt+1) (drained at b1 of jt+1)
            gl_lds16(vp0, vshf + (kc0 << 9));
            gl_lds16(vp1, vshf + (kc1 << 9));
            vp0 += 64; vp1 += 64;
        }
        const int t = s0; s0 = s1; s1 = s2; s2 = t;  // rotate ring
    }

    // ---- epilogue: normalize, write ob bf16 [b][i][d] ----
#pragma unroll
    for (int ct = 0; ct < 4; ++ct) {
#pragma unroll
        for (int r = 0; r < 4; ++r) {
            const int i = i0 + (w << 4) + (quad << 2) + r;
            const float val = o_acc[ct][r] / l_r[r];
            ob[((size_t)b * T_DIM + i) * D_DIM + h * DH + (ct << 4) + l15] = f2bf(val);
        }
    }
}

// ---------------------------------------------------------------------------
extern "C" void kernel_launch(void* const* d_in, const int* in_sizes, int n_in,
                              void* d_out, int out_size, void* d_ws, size_t ws_size,
                              hipStream_t stream) {
    const float* x = (const float*)d_in[0];
    const float* mem = (const float*)d_in[1];
    const float* wq = (const float*)d_in[2];
    const float* wkv = (const float*)d_in[3];
    const float* wo = (const float*)d_in[4];
    const float* bo = (const float*)d_in[5];
    const float* rel_w = (const float*)d_in[6];

    float* out = (float*)d_out;
    float* mem_next = out + (size_t)B_DIM * T_DIM * D_DIM;

    // workspace layout (shorts), ~80 MB total
    short* kvb = (short*)d_ws;       // 8,388,608  [b][j][d] bf16
    short* qb = kvb + 8388608;       // 4,194,304  [bh][i][c]
    short* kb = qb + 4194304;        // 8,388,608  [bh][j][c]
    short* vTb = kb + 8388608;       // 8,388,608  [bh][c][j]
    short* relb = vTb + 8388608;     // 2,228,224  [h][jp][c]
    short* ob = relb + 2228224;      // 4,194,304  [b*i][d]
    short* wkvqT = ob + 4194304;     // 3,145,728  [3072][1024]
    short* woT = wkvqT + 3145728;    // 1,048,576  [1024][1024]

    // mem_next = x; kvb = bf16(concat(mem, x))
    hipLaunchKernelGGL(prep_xmem, dim3(8192), dim3(256), 0, stream,
                       x, mem, mem_next, kvb);

    // weight transposes -> bf16 [n][k] (wkv+wq concat, wo)
    hipLaunchKernelGGL(transpose_w3, dim3(32, 64, 3), dim3(32, 8), 0, stream,
                       wq, wkv, wo, wkvqT, woT);

    // rel_w -> relb bf16 [h][jp][c] (padded)
    hipLaunchKernelGGL(convert_rel, dim3(RELPAD / 16, H_DIM), dim3(256), 0, stream,
                       rel_w, relb);

    // fused kvq GEMM: kvin @ [wkv|wq] -> kb, vTb, qb
    hipLaunchKernelGGL((mfma_gemm<1>), dim3(24, 64), dim3(256), 0, stream,
                       kvb, wkvqT, nullptr, kb, vTb, qb, nullptr);

    // flash attention -> ob bf16
    hipLaunchKernelGGL(flash_attn, dim3(16, 64), dim3(256), 0, stream,
                       qb, kb, vTb, relb, ob);

    // out = ob @ wo + bo -> fp32
    hipLaunchKernelGGL((mfma_gemm<2>), dim3(8, 32), dim3(256), 0, stream,
                       ob, woT, bo, nullptr, nullptr, nullptr, out);
}